// Round 1
// baseline (1516.768 us; speedup 1.0000x reference)
//
#include <hip/hip_runtime.h>
#include <stdint.h>

#define N_NODES 50000
#define D_MODEL 768
#define N_EDGES 100000
#define BM 128
#define BK 32
#define NKT 24                 /* 768/32 */
#define MBLOCKS 391            /* ceil(50000/128) */
#define M_PAD (MBLOCKS * BM)   /* 50048 */
#define NCB 6                  /* 768/128 */
#define TILE_BYTES 8192        /* 128*32*2 */

typedef unsigned short ushort_t;
typedef __bf16 bf16x8 __attribute__((ext_vector_type(8)));
typedef float f32x4 __attribute__((ext_vector_type(4)));

__device__ __forceinline__ unsigned short f2bf(float f) {
  union { float f; unsigned u; } v; v.f = f;
  unsigned r = v.u + 0x7fffu + ((v.u >> 16) & 1u);
  return (unsigned short)(r >> 16);
}

__device__ __forceinline__ void gload_lds16(const void* g, void* l) {
  __builtin_amdgcn_global_load_lds(
      (const __attribute__((address_space(1))) unsigned int*)g,
      (__attribute__((address_space(3))) unsigned int*)l, 16, 0, 0);
}

// ---- edge-index dtype detection (int32 vs int64) ----
__global__ void k_detect(const unsigned* __restrict__ e, int* flag) {
  int is64 = 1;
  for (int i = 0; i < 64; ++i)
    if (e[2 * i + 1] != 0u) { is64 = 0; break; }
  *flag = is64;
}

__device__ __forceinline__ int eidx(const unsigned* e, int logical, int is64) {
  return is64 ? (int)e[2 * logical] : (int)e[logical];
}

// ---- degree / dinv / colsum init ----
__global__ void k_init(float* deg, float* colsum) {
  int i = blockIdx.x * 256 + threadIdx.x;
  if (i < N_NODES) deg[i] = 1.0f;
  if (i < D_MODEL) colsum[i] = 0.0f;
}

__global__ void k_deg(const unsigned* __restrict__ e, const int* __restrict__ eflag,
                      float* deg) {
  int i = blockIdx.x * 256 + threadIdx.x;
  if (i >= N_EDGES) return;
  int is64 = *eflag;
  int d = eidx(e, N_EDGES + i, is64);
  atomicAdd(&deg[d], 1.0f);
}

__global__ void k_rsqrt(float* deg) {
  int i = blockIdx.x * 256 + threadIdx.x;
  if (i < N_NODES) deg[i] = rsqrtf(deg[i]);
}

// ---- pack W (f32 [768][768] row-major -> bf16 fragment-major tiles) ----
// layout: [cb(6)][kt(24)][cb16(8)][g(4)][c(16)] x 16B units; within a unit,
// byte j*2 holds k = kt*32 + g*4 + (j&3) + 16*(j>>2), col = cb*128+cb16*16+c
__global__ void k_pack_w(const float* __restrict__ W, ushort_t* __restrict__ pw) {
  int u = blockIdx.x * 256 + threadIdx.x;   // 73728 units
  if (u >= 6 * 24 * 8 * 64) return;
  int c    = u & 15;
  int g    = (u >> 4) & 3;
  int cb16 = (u >> 6) & 7;
  int kt   = (u >> 9) % NKT;
  int cb   = u / (512 * NKT);
  int col  = cb * 128 + cb16 * 16 + c;
  ushort_t o[8];
#pragma unroll
  for (int j = 0; j < 8; ++j) {
    int k = kt * 32 + g * 4 + (j & 3) + 16 * (j >> 2);
    o[j] = f2bf(W[(size_t)k * D_MODEL + col]);
  }
  uint2 w0, w1;
  w0.x = (unsigned)o[0] | ((unsigned)o[1] << 16);
  w0.y = (unsigned)o[2] | ((unsigned)o[3] << 16);
  w1.x = (unsigned)o[4] | ((unsigned)o[5] << 16);
  w1.y = (unsigned)o[6] | ((unsigned)o[7] << 16);
  uint2* dst = (uint2*)(pw + (size_t)u * 8);
  dst[0] = w0; dst[1] = w1;
}

// ---- pack A (f32 [N][768] -> bf16 fragment-major tiles, optional relu) ----
// layout: [bm(391)][kt(24)] tiles of 8KB: [rb16(8)][g(4)][r(16)] 16B units
__global__ void k_pack_a(const float* __restrict__ X, ushort_t* __restrict__ pa,
                         int apply_relu) {
  __shared__ __align__(16) ushort_t sm[BM * BK];  // 8KB
  int bm = blockIdx.x, kt = blockIdx.y;
  int t = threadIdx.x;
#pragma unroll
  for (int i = 0; i < 4; ++i) {
    int idx = i * 256 + t;        // 0..1023 float4 units
    int row_l = idx >> 3;
    int q = idx & 7;              // which float4 in the 32-k row
    int row = bm * BM + row_l;
    float4 v = make_float4(0.f, 0.f, 0.f, 0.f);
    if (row < N_NODES)
      v = *(const float4*)(X + (size_t)row * D_MODEL + kt * 32 + q * 4);
    if (apply_relu) {
      v.x = fmaxf(v.x, 0.f); v.y = fmaxf(v.y, 0.f);
      v.z = fmaxf(v.z, 0.f); v.w = fmaxf(v.w, 0.f);
    }
    uint2 p;
    p.x = (unsigned)f2bf(v.x) | ((unsigned)f2bf(v.y) << 16);
    p.y = (unsigned)f2bf(v.z) | ((unsigned)f2bf(v.w) << 16);
    // element offset: rb16*512 + g*128 + r*8 + half*4   (elements are 2B)
    int off = (row_l >> 4) * 512 + (q & 3) * 128 + (row_l & 15) * 8 + (q >> 2) * 4;
    *(uint2*)(sm + off) = p;
  }
  __syncthreads();
  const uint4* s4 = (const uint4*)sm;           // 512 units
  uint4* d4 = (uint4*)pa + ((size_t)bm * NKT + kt) * 512;
  d4[t] = s4[t];
  d4[t + 256] = s4[t + 256];
}

// ---- GEMM: C[M_PAD x 768] = A(bf16) @ W(bf16); epilogue writes raw h to tmp
//      and h*dinv^2 + bias to agg ----
__global__ __launch_bounds__(256) void k_gemm(
    const ushort_t* __restrict__ pa, const ushort_t* __restrict__ pw,
    const float* __restrict__ dinv, const float* __restrict__ bias,
    float* __restrict__ tmp, float* __restrict__ agg) {
  __shared__ __align__(16) char smem[2 * TILE_BYTES];  // A @0, B @8192
  int bm = blockIdx.x, cb = blockIdx.y;
  int t = threadIdx.x, w = t >> 6, l = t & 63;
  int wm = w >> 1, wn = w & 1;
  int g = l >> 4, r16 = l & 15;

  f32x4 acc[4][4] = {};

  const char* paT = (const char*)pa + (size_t)bm * NKT * TILE_BYTES;
  const char* pwT = (const char*)pw + (size_t)cb * NKT * TILE_BYTES;

  for (int kt = 0; kt < NKT; ++kt) {
    const char* ga = paT + (size_t)kt * TILE_BYTES;
    const char* gb = pwT + (size_t)kt * TILE_BYTES;
    int u = w * 2;
    gload_lds16(ga + (size_t)u * 1024 + (size_t)l * 16,       &smem[u * 1024]);
    gload_lds16(ga + (size_t)(u + 1) * 1024 + (size_t)l * 16, &smem[(u + 1) * 1024]);
    gload_lds16(gb + (size_t)u * 1024 + (size_t)l * 16,       &smem[TILE_BYTES + u * 1024]);
    gload_lds16(gb + (size_t)(u + 1) * 1024 + (size_t)l * 16, &smem[TILE_BYTES + (u + 1) * 1024]);
    __builtin_amdgcn_s_waitcnt(0);
    __syncthreads();

    bf16x8 af[4], bfr[4];
#pragma unroll
    for (int m = 0; m < 4; ++m)
      af[m] = *(const bf16x8*)&smem[(wm * 4 + m) * 1024 + g * 256 + r16 * 16];
#pragma unroll
    for (int n = 0; n < 4; ++n)
      bfr[n] = *(const bf16x8*)&smem[TILE_BYTES + (wn * 4 + n) * 1024 + g * 256 + r16 * 16];
#pragma unroll
    for (int m = 0; m < 4; ++m)
#pragma unroll
      for (int n = 0; n < 4; ++n)
        acc[m][n] = __builtin_amdgcn_mfma_f32_16x16x32_bf16(af[m], bfr[n], acc[m][n], 0, 0, 0);
    __syncthreads();
  }

  int colb = cb * 128 + wn * 64;
#pragma unroll
  for (int m = 0; m < 4; ++m) {
#pragma unroll
    for (int reg = 0; reg < 4; ++reg) {
      int row = bm * BM + wm * 64 + m * 16 + g * 4 + reg;
      if (row >= N_NODES) continue;
      float di = dinv[row];
      float d2 = di * di;
      size_t base = (size_t)row * D_MODEL + colb;
#pragma unroll
      for (int n = 0; n < 4; ++n) {
        int col = n * 16 + r16;
        float v = acc[m][n][reg];
        tmp[base + col] = v;
        agg[base + col] = v * d2 + bias[colb + col];
      }
    }
  }
}

// ---- edge scatter: agg[dst] += tmp[src] * dinv[src]*dinv[dst] ----
__global__ void k_scatter(const unsigned* __restrict__ e, const int* __restrict__ eflag,
                          const float* __restrict__ dinv, const float* __restrict__ tmp,
                          float* __restrict__ agg) {
  int ed = blockIdx.x;
  int is64 = *eflag;
  int s = eidx(e, ed, is64);
  int d = eidx(e, N_EDGES + ed, is64);
  float norm = dinv[s] * dinv[d];
  const float* hs = tmp + (size_t)s * D_MODEL;
  float* ad = agg + (size_t)d * D_MODEL;
#pragma unroll
  for (int j = 0; j < 3; ++j) {
    int c = threadIdx.x + j * 256;
    atomicAdd(&ad[c], hs[c] * norm);
  }
}

// ---- residual + relu + column-sum ----
#define RROWS 64
__global__ void k_resid(float* __restrict__ h, const float* __restrict__ x,
                        float* __restrict__ colsum) {
  int r0 = blockIdx.x * RROWS;
  int t = threadIdx.x;
  float s0 = 0.f, s1 = 0.f, s2 = 0.f;
  int rend = r0 + RROWS; if (rend > N_NODES) rend = N_NODES;
  for (int r = r0; r < rend; ++r) {
    size_t b = (size_t)r * D_MODEL;
    float v0 = fmaxf(h[b + t], 0.f) + x[b + t];
    float v1 = fmaxf(h[b + t + 256], 0.f) + x[b + t + 256];
    float v2 = fmaxf(h[b + t + 512], 0.f) + x[b + t + 512];
    h[b + t] = v0; h[b + t + 256] = v1; h[b + t + 512] = v2;
    s0 += v0; s1 += v1; s2 += v2;
  }
  atomicAdd(&colsum[t], s0);
  atomicAdd(&colsum[t + 256], s1);
  atomicAdd(&colsum[t + 512], s2);
}

// ---- final: out = (colsum/N) @ Wl + bl ----
__global__ void k_final(const float* __restrict__ colsum, const float* __restrict__ Wl,
                        const float* __restrict__ bl, float* __restrict__ out) {
  int j = blockIdx.x * 256 + threadIdx.x;
  if (j >= D_MODEL) return;
  float s = 0.f;
  for (int k = 0; k < D_MODEL; ++k)
    s += colsum[k] * Wl[(size_t)k * D_MODEL + j];
  out[j] = s * (1.0f / (float)N_NODES) + bl[j];
}

extern "C" void kernel_launch(void* const* d_in, const int* in_sizes, int n_in,
                              void* d_out, int out_size, void* d_ws, size_t ws_size,
                              hipStream_t stream) {
  const float* x      = (const float*)d_in[0];
  const unsigned* edg = (const unsigned*)d_in[1];
  const float* W1 = (const float*)d_in[2];
  const float* b1 = (const float*)d_in[3];
  const float* W2 = (const float*)d_in[4];
  const float* b2 = (const float*)d_in[5];
  const float* W3 = (const float*)d_in[6];
  const float* b3 = (const float*)d_in[7];
  const float* Wl = (const float*)d_in[8];
  const float* bl = (const float*)d_in[9];

  float* hout = (float*)d_out;
  float* oout = hout + (size_t)N_NODES * D_MODEL;

  char* ws = (char*)d_ws;
  size_t off = 0;
  float* tmp = (float*)(ws + off);      off += (size_t)N_NODES * D_MODEL * 4;  // 153.6 MB
  ushort_t* pa = (ushort_t*)(ws + off); off += (size_t)M_PAD * D_MODEL * 2;    // 76.9 MB
  ushort_t* pw0 = (ushort_t*)(ws + off); off += (size_t)D_MODEL * D_MODEL * 2;
  ushort_t* pw1 = (ushort_t*)(ws + off); off += (size_t)D_MODEL * D_MODEL * 2;
  ushort_t* pw2 = (ushort_t*)(ws + off); off += (size_t)D_MODEL * D_MODEL * 2;
  float* dinv = (float*)(ws + off);     off += (((size_t)N_NODES * 4 + 255) / 256) * 256;
  float* colsum = (float*)(ws + off);   off += 1024;
  int* eflag = (int*)(ws + off);        off += 256;

  k_detect<<<1, 1, 0, stream>>>(edg, eflag);
  k_init<<<196, 256, 0, stream>>>(dinv, colsum);
  k_deg<<<391, 256, 0, stream>>>(edg, eflag, dinv);
  k_rsqrt<<<196, 256, 0, stream>>>(dinv);
  k_pack_w<<<288, 256, 0, stream>>>(W1, pw0);
  k_pack_w<<<288, 256, 0, stream>>>(W2, pw1);
  k_pack_w<<<288, 256, 0, stream>>>(W3, pw2);

  const float* biases[3] = {b1, b2, b3};
  const ushort_t* pws[3] = {pw0, pw1, pw2};
  for (int layer = 0; layer < 3; ++layer) {
    k_pack_a<<<dim3(MBLOCKS, NKT), 256, 0, stream>>>(layer == 0 ? x : hout, pa, layer > 0);
    k_gemm<<<dim3(MBLOCKS, NCB), 256, 0, stream>>>(pa, pws[layer], dinv, biases[layer], tmp, hout);
    k_scatter<<<N_EDGES, 256, 0, stream>>>(edg, eflag, dinv, tmp, hout);
  }
  k_resid<<<782, 256, 0, stream>>>(hout, x, colsum);
  k_final<<<3, 256, 0, stream>>>(colsum, Wl, bl, oout);
}

// Round 2
// 953.799 us; speedup vs baseline: 1.5902x; 1.5902x over previous
//
#include <hip/hip_runtime.h>
#include <stdint.h>

#define N_NODES 50000
#define D_MODEL 768
#define N_EDGES 100000
#define BM 128
#define BK 32
#define NKT 24                 /* 768/32 */
#define MBLOCKS 391            /* ceil(50000/128) */
#define M_PAD (MBLOCKS * BM)   /* 50048 */
#define NCB 6                  /* 768/128 */
#define TILE_BYTES 8192        /* 128*32*2 */

typedef unsigned short ushort_t;
typedef __bf16 bf16x8 __attribute__((ext_vector_type(8)));
typedef float f32x4 __attribute__((ext_vector_type(4)));

__device__ __forceinline__ unsigned short f2bf(float f) {
  union { float f; unsigned u; } v; v.f = f;
  unsigned r = v.u + 0x7fffu + ((v.u >> 16) & 1u);
  return (unsigned short)(r >> 16);
}

__device__ __forceinline__ void gload_lds16(const void* g, void* l) {
  __builtin_amdgcn_global_load_lds(
      (const __attribute__((address_space(1))) unsigned int*)g,
      (__attribute__((address_space(3))) unsigned int*)l, 16, 0, 0);
}

// ---- edge-index dtype detection (int32 vs int64) ----
__global__ void k_detect(const unsigned* __restrict__ e, int* flag) {
  int is64 = 1;
  for (int i = 0; i < 64; ++i)
    if (e[2 * i + 1] != 0u) { is64 = 0; break; }
  *flag = is64;
}

__device__ __forceinline__ int eidx(const unsigned* e, int logical, int is64) {
  return is64 ? (int)e[2 * logical] : (int)e[logical];
}

// ---- init: zero in-degree counts + colsum ----
__global__ void k_init(int* counts, float* colsum) {
  int i = blockIdx.x * 256 + threadIdx.x;
  if (i < N_NODES) counts[i] = 0;
  if (i < D_MODEL) colsum[i] = 0.0f;
}

__global__ void k_count(const unsigned* __restrict__ e, const int* __restrict__ eflag,
                        int* counts) {
  int i = blockIdx.x * 256 + threadIdx.x;
  if (i >= N_EDGES) return;
  int is64 = *eflag;
  int d = eidx(e, N_EDGES + i, is64);
  atomicAdd(&counts[d], 1);
}

// ---- CSR build: 3-phase exclusive scan of counts -> rowptr, then fill ----
__global__ void k_scan1(const int* __restrict__ counts, int* rowptr, int* bsum,
                        float* dinv) {
  __shared__ int sm[256];
  int b = blockIdx.x, t = threadIdx.x;
  int i = b * 256 + t;
  int v = (i < N_NODES) ? counts[i] : 0;
  if (i < N_NODES) dinv[i] = rsqrtf((float)(v + 1));  // deg = 1 + indeg
  sm[t] = v;
  __syncthreads();
#pragma unroll
  for (int off = 1; off < 256; off <<= 1) {
    int x = (t >= off) ? sm[t - off] : 0;
    __syncthreads();
    sm[t] += x;
    __syncthreads();
  }
  if (i < N_NODES) rowptr[i] = sm[t] - v;   // exclusive
  if (t == 255) bsum[b] = sm[255];
}

__global__ void k_scan2(int* bsum, int* boff) {
  __shared__ int sm[256];
  int t = threadIdx.x;
  int v = (t < 196) ? bsum[t] : 0;
  sm[t] = v;
  __syncthreads();
#pragma unroll
  for (int off = 1; off < 256; off <<= 1) {
    int x = (t >= off) ? sm[t - off] : 0;
    __syncthreads();
    sm[t] += x;
    __syncthreads();
  }
  boff[t] = sm[t] - v;  // exclusive
}

__global__ void k_scan3(int* rowptr, const int* __restrict__ boff, int* counts) {
  int b = blockIdx.x, t = threadIdx.x;
  int i = b * 256 + t;
  if (i < N_NODES) {
    rowptr[i] += boff[b];
    counts[i] = 0;       // reuse as fill cursor
  }
  if (i == 0) rowptr[N_NODES] = N_EDGES;
}

__global__ void k_fill(const unsigned* __restrict__ e, const int* __restrict__ eflag,
                       const int* __restrict__ rowptr, int* counts, int* csr) {
  int i = blockIdx.x * 256 + threadIdx.x;
  if (i >= N_EDGES) return;
  int is64 = *eflag;
  int s = eidx(e, i, is64);
  int d = eidx(e, N_EDGES + i, is64);
  int pos = atomicAdd(&counts[d], 1);
  csr[rowptr[d] + pos] = s;
}

// ---- pack W (f32 [768][768] row-major -> bf16 fragment-major tiles) ----
__global__ void k_pack_w(const float* __restrict__ W, ushort_t* __restrict__ pw) {
  int u = blockIdx.x * 256 + threadIdx.x;   // 73728 units
  if (u >= 6 * 24 * 8 * 64) return;
  int c    = u & 15;
  int g    = (u >> 4) & 3;
  int cb16 = (u >> 6) & 7;
  int kt   = (u >> 9) % NKT;
  int cb   = u / (512 * NKT);
  int col  = cb * 128 + cb16 * 16 + c;
  ushort_t o[8];
#pragma unroll
  for (int j = 0; j < 8; ++j) {
    int k = kt * 32 + g * 4 + (j & 3) + 16 * (j >> 2);
    o[j] = f2bf(W[(size_t)k * D_MODEL + col]);
  }
  uint2 w0, w1;
  w0.x = (unsigned)o[0] | ((unsigned)o[1] << 16);
  w0.y = (unsigned)o[2] | ((unsigned)o[3] << 16);
  w1.x = (unsigned)o[4] | ((unsigned)o[5] << 16);
  w1.y = (unsigned)o[6] | ((unsigned)o[7] << 16);
  uint2* dst = (uint2*)(pw + (size_t)u * 8);
  dst[0] = w0; dst[1] = w1;
}

// ---- pack A (f32 [N][768] -> bf16 fragment-major tiles, optional relu) ----
__global__ void k_pack_a(const float* __restrict__ X, ushort_t* __restrict__ pa,
                         int apply_relu) {
  __shared__ __align__(16) ushort_t sm[BM * BK];  // 8KB
  int bm = blockIdx.x, kt = blockIdx.y;
  int t = threadIdx.x;
#pragma unroll
  for (int i = 0; i < 4; ++i) {
    int idx = i * 256 + t;        // 0..1023 float4 units
    int row_l = idx >> 3;
    int q = idx & 7;              // which float4 in the 32-k row
    int row = bm * BM + row_l;
    float4 v = make_float4(0.f, 0.f, 0.f, 0.f);
    if (row < N_NODES)
      v = *(const float4*)(X + (size_t)row * D_MODEL + kt * 32 + q * 4);
    if (apply_relu) {
      v.x = fmaxf(v.x, 0.f); v.y = fmaxf(v.y, 0.f);
      v.z = fmaxf(v.z, 0.f); v.w = fmaxf(v.w, 0.f);
    }
    uint2 p;
    p.x = (unsigned)f2bf(v.x) | ((unsigned)f2bf(v.y) << 16);
    p.y = (unsigned)f2bf(v.z) | ((unsigned)f2bf(v.w) << 16);
    int off = (row_l >> 4) * 512 + (q & 3) * 128 + (row_l & 15) * 8 + (q >> 2) * 4;
    *(uint2*)(sm + off) = p;
  }
  __syncthreads();
  const uint4* s4 = (const uint4*)sm;           // 512 units
  uint4* d4 = (uint4*)pa + ((size_t)bm * NKT + kt) * 512;
  d4[t] = s4[t];
  d4[t + 256] = s4[t + 256];
}

// ---- GEMM: tmp'[row] = (A@W)[row] * dinv[row]  (bf16 MFMA, f32 out) ----
__global__ __launch_bounds__(256) void k_gemm(
    const ushort_t* __restrict__ pa, const ushort_t* __restrict__ pw,
    const float* __restrict__ dinv, float* __restrict__ tmp) {
  __shared__ __align__(16) char smem[2 * TILE_BYTES];  // A @0, B @8192
  int cb = blockIdx.x, bm = blockIdx.y;
  int t = threadIdx.x, w = t >> 6, l = t & 63;
  int wm = w >> 1, wn = w & 1;
  int g = l >> 4, r16 = l & 15;

  f32x4 acc[4][4] = {};

  const char* paT = (const char*)pa + (size_t)bm * NKT * TILE_BYTES;
  const char* pwT = (const char*)pw + (size_t)cb * NKT * TILE_BYTES;

  for (int kt = 0; kt < NKT; ++kt) {
    const char* ga = paT + (size_t)kt * TILE_BYTES;
    const char* gb = pwT + (size_t)kt * TILE_BYTES;
    int u = w * 2;
    gload_lds16(ga + (size_t)u * 1024 + (size_t)l * 16,       &smem[u * 1024]);
    gload_lds16(ga + (size_t)(u + 1) * 1024 + (size_t)l * 16, &smem[(u + 1) * 1024]);
    gload_lds16(gb + (size_t)u * 1024 + (size_t)l * 16,       &smem[TILE_BYTES + u * 1024]);
    gload_lds16(gb + (size_t)(u + 1) * 1024 + (size_t)l * 16, &smem[TILE_BYTES + (u + 1) * 1024]);
    __builtin_amdgcn_s_waitcnt(0);
    __syncthreads();

    bf16x8 af[4], bfr[4];
#pragma unroll
    for (int m = 0; m < 4; ++m)
      af[m] = *(const bf16x8*)&smem[(wm * 4 + m) * 1024 + g * 256 + r16 * 16];
#pragma unroll
    for (int n = 0; n < 4; ++n)
      bfr[n] = *(const bf16x8*)&smem[TILE_BYTES + (wn * 4 + n) * 1024 + g * 256 + r16 * 16];
#pragma unroll
    for (int m = 0; m < 4; ++m)
#pragma unroll
      for (int n = 0; n < 4; ++n)
        acc[m][n] = __builtin_amdgcn_mfma_f32_16x16x32_bf16(af[m], bfr[n], acc[m][n], 0, 0, 0);
    __syncthreads();
  }

  int colb = cb * 128 + wn * 64;
#pragma unroll
  for (int m = 0; m < 4; ++m) {
#pragma unroll
    for (int reg = 0; reg < 4; ++reg) {
      int row = bm * BM + wm * 64 + m * 16 + g * 4 + reg;
      if (row >= N_NODES) continue;
      float di = dinv[row];
      size_t base = (size_t)row * D_MODEL + colb;
#pragma unroll
      for (int n = 0; n < 4; ++n)
        tmp[base + n * 16 + r16] = acc[m][n][reg] * di;
    }
  }
}

// ---- gather: hout[d] = dinv[d]*(tmp'[d] + sum_in tmp'[s]) + bias ----
#define GROWS 32
__global__ __launch_bounds__(256) void k_gather(
    const int* __restrict__ rowptr, const int* __restrict__ csr,
    const float* __restrict__ dinv, const float* __restrict__ bias,
    const float* __restrict__ tmp, float* __restrict__ hout) {
  int w = threadIdx.x >> 6, l = threadIdx.x & 63;
  const f32x4* b4 = (const f32x4*)bias;
  f32x4 bb0 = b4[l], bb1 = b4[l + 64], bb2 = b4[l + 128];
  for (int rr = w; rr < GROWS; rr += 4) {
    int r = blockIdx.x * GROWS + rr;
    if (r >= N_NODES) break;
    const f32x4* rp = (const f32x4*)(tmp + (size_t)r * D_MODEL);
    f32x4 a0 = rp[l], a1 = rp[l + 64], a2 = rp[l + 128];
    int beg = rowptr[r], end = rowptr[r + 1];
    for (int j = beg; j < end; ++j) {
      int s = csr[j];
      const f32x4* sp = (const f32x4*)(tmp + (size_t)s * D_MODEL);
      a0 += sp[l]; a1 += sp[l + 64]; a2 += sp[l + 128];
    }
    float di = dinv[r];
    f32x4* op = (f32x4*)(hout + (size_t)r * D_MODEL);
    op[l]       = a0 * di + bb0;
    op[l + 64]  = a1 * di + bb1;
    op[l + 128] = a2 * di + bb2;
  }
}

// ---- residual + relu + column-sum ----
#define RROWS 64
__global__ void k_resid(float* __restrict__ h, const float* __restrict__ x,
                        float* __restrict__ colsum) {
  int r0 = blockIdx.x * RROWS;
  int t = threadIdx.x;
  float s0 = 0.f, s1 = 0.f, s2 = 0.f;
  int rend = r0 + RROWS; if (rend > N_NODES) rend = N_NODES;
  for (int r = r0; r < rend; ++r) {
    size_t b = (size_t)r * D_MODEL;
    float v0 = fmaxf(h[b + t], 0.f) + x[b + t];
    float v1 = fmaxf(h[b + t + 256], 0.f) + x[b + t + 256];
    float v2 = fmaxf(h[b + t + 512], 0.f) + x[b + t + 512];
    h[b + t] = v0; h[b + t + 256] = v1; h[b + t + 512] = v2;
    s0 += v0; s1 += v1; s2 += v2;
  }
  atomicAdd(&colsum[t], s0);
  atomicAdd(&colsum[t + 256], s1);
  atomicAdd(&colsum[t + 512], s2);
}

// ---- final: out = (colsum/N) @ Wl + bl ----
__global__ void k_final(const float* __restrict__ colsum, const float* __restrict__ Wl,
                        const float* __restrict__ bl, float* __restrict__ out) {
  int j = blockIdx.x * 256 + threadIdx.x;
  if (j >= D_MODEL) return;
  float s = 0.f;
  for (int k = 0; k < D_MODEL; ++k)
    s += colsum[k] * Wl[(size_t)k * D_MODEL + j];
  out[j] = s * (1.0f / (float)N_NODES) + bl[j];
}

extern "C" void kernel_launch(void* const* d_in, const int* in_sizes, int n_in,
                              void* d_out, int out_size, void* d_ws, size_t ws_size,
                              hipStream_t stream) {
  const float* x      = (const float*)d_in[0];
  const unsigned* edg = (const unsigned*)d_in[1];
  const float* W1 = (const float*)d_in[2];
  const float* b1 = (const float*)d_in[3];
  const float* W2 = (const float*)d_in[4];
  const float* b2 = (const float*)d_in[5];
  const float* W3 = (const float*)d_in[6];
  const float* b3 = (const float*)d_in[7];
  const float* Wl = (const float*)d_in[8];
  const float* bl = (const float*)d_in[9];

  float* hout = (float*)d_out;
  float* oout = hout + (size_t)N_NODES * D_MODEL;

  char* ws = (char*)d_ws;
  size_t off = 0;
  float* tmp = (float*)(ws + off);       off += (size_t)N_NODES * D_MODEL * 4;  // 153.6 MB
  ushort_t* pa = (ushort_t*)(ws + off);  off += (size_t)M_PAD * D_MODEL * 2;    // 76.9 MB
  ushort_t* pw0 = (ushort_t*)(ws + off); off += (size_t)D_MODEL * D_MODEL * 2;
  ushort_t* pw1 = (ushort_t*)(ws + off); off += (size_t)D_MODEL * D_MODEL * 2;
  ushort_t* pw2 = (ushort_t*)(ws + off); off += (size_t)D_MODEL * D_MODEL * 2;
  float* dinv = (float*)(ws + off);      off += 50176 * 4;
  int* counts = (int*)(ws + off);        off += 50176 * 4;
  int* rowptr = (int*)(ws + off);        off += 50304 * 4;
  int* csr = (int*)(ws + off);           off += (size_t)N_EDGES * 4;
  int* bsum = (int*)(ws + off);          off += 256 * 4;
  int* boff = (int*)(ws + off);          off += 256 * 4;
  float* colsum = (float*)(ws + off);    off += 1024;
  int* eflag = (int*)(ws + off);         off += 256;

  // setup (edge structure is static across layers)
  k_detect<<<1, 1, 0, stream>>>(edg, eflag);
  k_init<<<196, 256, 0, stream>>>(counts, colsum);
  k_count<<<391, 256, 0, stream>>>(edg, eflag, counts);
  k_scan1<<<196, 256, 0, stream>>>(counts, rowptr, bsum, dinv);
  k_scan2<<<1, 256, 0, stream>>>(bsum, boff);
  k_scan3<<<196, 256, 0, stream>>>(rowptr, boff, counts);
  k_fill<<<391, 256, 0, stream>>>(edg, eflag, rowptr, counts, csr);
  k_pack_w<<<288, 256, 0, stream>>>(W1, pw0);
  k_pack_w<<<288, 256, 0, stream>>>(W2, pw1);
  k_pack_w<<<288, 256, 0, stream>>>(W3, pw2);

  const float* biases[3] = {b1, b2, b3};
  const ushort_t* pws[3] = {pw0, pw1, pw2};
  for (int layer = 0; layer < 3; ++layer) {
    k_pack_a<<<dim3(MBLOCKS, NKT), 256, 0, stream>>>(layer == 0 ? x : hout, pa, layer > 0);
    k_gemm<<<dim3(NCB, MBLOCKS), 256, 0, stream>>>(pa, pws[layer], dinv, tmp);
    k_gather<<<(N_NODES + GROWS - 1) / GROWS, 256, 0, stream>>>(
        rowptr, csr, dinv, biases[layer], tmp, hout);
  }
  k_resid<<<782, 256, 0, stream>>>(hout, x, colsum);
  k_final<<<3, 256, 0, stream>>>(colsum, Wl, bl, oout);
}

// Round 3
// 799.543 us; speedup vs baseline: 1.8970x; 1.1929x over previous
//
#include <hip/hip_runtime.h>
#include <stdint.h>

#define N_NODES 50000
#define D_MODEL 768
#define N_EDGES 100000
#define BM 128
#define BK 32
#define NKT 24                 /* 768/32 */
#define MBLOCKS 391            /* ceil(50000/128) */
#define M_PAD (MBLOCKS * BM)   /* 50048 */
#define NCB 6                  /* 768/128 */
#define TILE_BYTES 8192        /* 128*32*2 */
#define TILE_ELEMS 4096
#define NWG (MBLOCKS * NCB)    /* 2346 */
#define GROWS 32

typedef unsigned short ushort_t;
typedef __bf16 bf16x8 __attribute__((ext_vector_type(8)));
typedef float f32x4 __attribute__((ext_vector_type(4)));

__device__ __forceinline__ unsigned short f2bf(float f) {
  union { float f; unsigned u; } v; v.f = f;
  unsigned r = v.u + 0x7fffu + ((v.u >> 16) & 1u);
  return (unsigned short)(r >> 16);
}

__device__ __forceinline__ uint2 pack4(f32x4 v) {
  uint2 p;
  p.x = (unsigned)f2bf(v[0]) | ((unsigned)f2bf(v[1]) << 16);
  p.y = (unsigned)f2bf(v[2]) | ((unsigned)f2bf(v[3]) << 16);
  return p;
}

__device__ __forceinline__ f32x4 relu4(f32x4 v) {
#pragma unroll
  for (int c = 0; c < 4; ++c) v[c] = fmaxf(v[c], 0.f);
  return v;
}

__device__ __forceinline__ void gload_lds16(const void* g, void* l) {
  __builtin_amdgcn_global_load_lds(
      (const __attribute__((address_space(1))) unsigned int*)g,
      (__attribute__((address_space(3))) unsigned int*)l, 16, 0, 0);
}

// ---- edge-index dtype detection (int32 vs int64) ----
__global__ void k_detect(const unsigned* __restrict__ e, int* flag) {
  int is64 = 1;
  for (int i = 0; i < 64; ++i)
    if (e[2 * i + 1] != 0u) { is64 = 0; break; }
  *flag = is64;
}

__device__ __forceinline__ int eidx(const unsigned* e, int logical, int is64) {
  return is64 ? (int)e[2 * logical] : (int)e[logical];
}

// ---- init: zero in-degree counts + colsum ----
__global__ void k_init(int* counts, float* colsum) {
  int i = blockIdx.x * 256 + threadIdx.x;
  if (i < N_NODES) counts[i] = 0;
  if (i < D_MODEL) colsum[i] = 0.0f;
}

__global__ void k_count(const unsigned* __restrict__ e, const int* __restrict__ eflag,
                        int* counts) {
  int i = blockIdx.x * 256 + threadIdx.x;
  if (i >= N_EDGES) return;
  int is64 = *eflag;
  int d = eidx(e, N_EDGES + i, is64);
  atomicAdd(&counts[d], 1);
}

// ---- CSR build: 3-phase exclusive scan of counts -> rowptr, then fill ----
__global__ void k_scan1(const int* __restrict__ counts, int* rowptr, int* bsum,
                        float* dinv) {
  __shared__ int sm[256];
  int b = blockIdx.x, t = threadIdx.x;
  int i = b * 256 + t;
  int v = (i < N_NODES) ? counts[i] : 0;
  if (i < N_NODES) dinv[i] = rsqrtf((float)(v + 1));  // deg = 1 + indeg
  sm[t] = v;
  __syncthreads();
#pragma unroll
  for (int off = 1; off < 256; off <<= 1) {
    int x = (t >= off) ? sm[t - off] : 0;
    __syncthreads();
    sm[t] += x;
    __syncthreads();
  }
  if (i < N_NODES) rowptr[i] = sm[t] - v;   // exclusive
  if (t == 255) bsum[b] = sm[255];
}

__global__ void k_scan2(int* bsum, int* boff) {
  __shared__ int sm[256];
  int t = threadIdx.x;
  int v = (t < 196) ? bsum[t] : 0;
  sm[t] = v;
  __syncthreads();
#pragma unroll
  for (int off = 1; off < 256; off <<= 1) {
    int x = (t >= off) ? sm[t - off] : 0;
    __syncthreads();
    sm[t] += x;
    __syncthreads();
  }
  boff[t] = sm[t] - v;  // exclusive
}

__global__ void k_scan3(int* rowptr, const int* __restrict__ boff, int* counts) {
  int b = blockIdx.x, t = threadIdx.x;
  int i = b * 256 + t;
  if (i < N_NODES) {
    rowptr[i] += boff[b];
    counts[i] = 0;       // reuse as fill cursor
  }
  if (i == 0) rowptr[N_NODES] = N_EDGES;
}

__global__ void k_fill(const unsigned* __restrict__ e, const int* __restrict__ eflag,
                       const int* __restrict__ rowptr, int* counts, int* csr) {
  int i = blockIdx.x * 256 + threadIdx.x;
  if (i >= N_EDGES) return;
  int is64 = *eflag;
  int s = eidx(e, i, is64);
  int d = eidx(e, N_EDGES + i, is64);
  int pos = atomicAdd(&counts[d], 1);
  csr[rowptr[d] + pos] = s;
}

// ---- pack W (f32 [768][768] row-major -> bf16 fragment-major tiles) ----
__global__ void k_pack_w(const float* __restrict__ W, ushort_t* __restrict__ pw) {
  int u = blockIdx.x * 256 + threadIdx.x;   // 73728 units
  if (u >= 6 * 24 * 8 * 64) return;
  int c    = u & 15;
  int g    = (u >> 4) & 3;
  int cb16 = (u >> 6) & 7;
  int kt   = (u >> 9) % NKT;
  int cb   = u / (512 * NKT);
  int col  = cb * 128 + cb16 * 16 + c;
  ushort_t o[8];
#pragma unroll
  for (int j = 0; j < 8; ++j) {
    int k = kt * 32 + g * 4 + (j & 3) + 16 * (j >> 2);
    o[j] = f2bf(W[(size_t)k * D_MODEL + col]);
  }
  uint2 w0, w1;
  w0.x = (unsigned)o[0] | ((unsigned)o[1] << 16);
  w0.y = (unsigned)o[2] | ((unsigned)o[3] << 16);
  w1.x = (unsigned)o[4] | ((unsigned)o[5] << 16);
  w1.y = (unsigned)o[6] | ((unsigned)o[7] << 16);
  uint2* dst = (uint2*)(pw + (size_t)u * 8);
  dst[0] = w0; dst[1] = w1;
}

// ---- pack A for layer 1 (x f32 [N][768] -> bf16 fragment-major tiles) ----
__global__ void k_pack_a_f32(const float* __restrict__ X, ushort_t* __restrict__ pa) {
  __shared__ __align__(16) ushort_t sm[BM * BK];  // 8KB
  int bm = blockIdx.x, kt = blockIdx.y;
  int t = threadIdx.x;
#pragma unroll
  for (int i = 0; i < 4; ++i) {
    int idx = i * 256 + t;        // 0..1023 float4 units
    int row_l = idx >> 3;
    int q = idx & 7;              // which float4 in the 32-k row
    int row = bm * BM + row_l;
    float4 v = make_float4(0.f, 0.f, 0.f, 0.f);
    if (row < N_NODES)
      v = *(const float4*)(X + (size_t)row * D_MODEL + kt * 32 + q * 4);
    uint2 p;
    p.x = (unsigned)f2bf(v.x) | ((unsigned)f2bf(v.y) << 16);
    p.y = (unsigned)f2bf(v.z) | ((unsigned)f2bf(v.w) << 16);
    int off = (row_l >> 4) * 512 + (q & 3) * 128 + (row_l & 15) * 8 + (q >> 2) * 4;
    *(uint2*)(sm + off) = p;
  }
  __syncthreads();
  const uint4* s4 = (const uint4*)sm;           // 512 units
  uint4* d4 = (uint4*)pa + ((size_t)bm * NKT + kt) * 512;
  d4[t] = s4[t];
  d4[t + 256] = s4[t + 256];
}

// ---- GEMM: tmp'[row] = (A@W)[row] * dinv[row]  (bf16 MFMA, f32 out) ----
// 1-D grid with bijective XCD-chunked swizzle (T1/m204): each XCD gets a
// contiguous bm-major range so an A-panel is fetched by exactly one L2.
__global__ __launch_bounds__(256) void k_gemm(
    const ushort_t* __restrict__ pa, const ushort_t* __restrict__ pw,
    const float* __restrict__ dinv, float* __restrict__ tmp) {
  __shared__ __align__(16) char smem[2 * TILE_BYTES];  // A @0, B @8192
  const int qq = NWG / 8, rm = NWG % 8;
  int orig = blockIdx.x;
  int xcd = orig & 7, idx = orig >> 3;
  int wgid = (xcd < rm ? xcd * (qq + 1) : rm * (qq + 1) + (xcd - rm) * qq) + idx;
  int bm = wgid / NCB, cb = wgid % NCB;

  int t = threadIdx.x, w = t >> 6, l = t & 63;
  int wm = w >> 1, wn = w & 1;
  int g = l >> 4, r16 = l & 15;

  f32x4 acc[4][4] = {};

  const char* paT = (const char*)pa + (size_t)bm * NKT * TILE_BYTES;
  const char* pwT = (const char*)pw + (size_t)cb * NKT * TILE_BYTES;

  for (int kt = 0; kt < NKT; ++kt) {
    const char* ga = paT + (size_t)kt * TILE_BYTES;
    const char* gb = pwT + (size_t)kt * TILE_BYTES;
    int u = w * 2;
    gload_lds16(ga + (size_t)u * 1024 + (size_t)l * 16,       &smem[u * 1024]);
    gload_lds16(ga + (size_t)(u + 1) * 1024 + (size_t)l * 16, &smem[(u + 1) * 1024]);
    gload_lds16(gb + (size_t)u * 1024 + (size_t)l * 16,       &smem[TILE_BYTES + u * 1024]);
    gload_lds16(gb + (size_t)(u + 1) * 1024 + (size_t)l * 16, &smem[TILE_BYTES + (u + 1) * 1024]);
    __builtin_amdgcn_s_waitcnt(0);
    __syncthreads();

    bf16x8 af[4], bfr[4];
#pragma unroll
    for (int m = 0; m < 4; ++m)
      af[m] = *(const bf16x8*)&smem[(wm * 4 + m) * 1024 + g * 256 + r16 * 16];
#pragma unroll
    for (int n = 0; n < 4; ++n)
      bfr[n] = *(const bf16x8*)&smem[TILE_BYTES + (wn * 4 + n) * 1024 + g * 256 + r16 * 16];
#pragma unroll
    for (int m = 0; m < 4; ++m)
#pragma unroll
      for (int n = 0; n < 4; ++n)
        acc[m][n] = __builtin_amdgcn_mfma_f32_16x16x32_bf16(af[m], bfr[n], acc[m][n], 0, 0, 0);
    __syncthreads();
  }

  int colb = cb * 128 + wn * 64;
#pragma unroll
  for (int m = 0; m < 4; ++m) {
#pragma unroll
    for (int reg = 0; reg < 4; ++reg) {
      int row = bm * BM + wm * 64 + m * 16 + g * 4 + reg;
      if (row >= N_NODES) continue;
      float di = dinv[row];
      size_t base = (size_t)row * D_MODEL + colb;
#pragma unroll
      for (int n = 0; n < 4; ++n)
        tmp[base + n * 16 + r16] = acc[m][n][reg] * di;
    }
  }
}

// ---- gather ----
// MODE 0 (layers 1,2): pa[r] = relu(dinv[r]*(tmp'[r]+sum_in tmp'[s]) + bias),
//                      written bf16 directly in MFMA-fragment-packed layout.
// MODE 1 (layer 3):    hout[r] = relu(...) + x[r] (f32), plus colsum reduce.
template <int MODE>
__global__ __launch_bounds__(256) void k_gather(
    const int* __restrict__ rowptr, const int* __restrict__ csr,
    const float* __restrict__ dinv, const float* __restrict__ bias,
    const float* __restrict__ tmp, ushort_t* __restrict__ pa,
    const float* __restrict__ x, float* __restrict__ hout,
    float* __restrict__ colsum) {
  __shared__ float cs[768];
  int t = threadIdx.x;
  if (MODE == 1) {
    cs[t] = 0.f; cs[t + 256] = 0.f; cs[t + 512] = 0.f;
    __syncthreads();
  }
  int w = t >> 6, l = t & 63;
  const f32x4* b4 = (const f32x4*)bias;
  f32x4 bb0 = b4[l], bb1 = b4[l + 64], bb2 = b4[l + 128];
  f32x4 s0 = {0.f, 0.f, 0.f, 0.f}, s1 = s0, s2 = s0;
  int kt0 = l >> 3, q = l & 7;
  int qoff = (q & 3) * 128 + (q >> 2) * 4;

  for (int rr = w; rr < GROWS; rr += 4) {
    int r = blockIdx.x * GROWS + rr;
    if (r >= N_NODES) break;
    const f32x4* rp = (const f32x4*)(tmp + (size_t)r * D_MODEL);
    f32x4 a0 = rp[l], a1 = rp[l + 64], a2 = rp[l + 128];
    int beg = rowptr[r], end = rowptr[r + 1];
    for (int j = beg; j < end; ++j) {
      int s = csr[j];
      const f32x4* sp = (const f32x4*)(tmp + (size_t)s * D_MODEL);
      a0 += sp[l]; a1 += sp[l + 64]; a2 += sp[l + 128];
    }
    float di = dinv[r];
    a0 = relu4(a0 * di + bb0);
    a1 = relu4(a1 * di + bb1);
    a2 = relu4(a2 * di + bb2);
    if (MODE == 0) {
      int bm = r >> 7, row_l = r & 127;
      size_t tb = ((size_t)bm * NKT + kt0) * TILE_ELEMS +
                  (row_l >> 4) * 512 + (row_l & 15) * 8 + qoff;
      *(uint2*)(pa + tb)                   = pack4(a0);
      *(uint2*)(pa + tb + 8 * TILE_ELEMS)  = pack4(a1);
      *(uint2*)(pa + tb + 16 * TILE_ELEMS) = pack4(a2);
    } else {
      const f32x4* xp = (const f32x4*)(x + (size_t)r * D_MODEL);
      a0 += xp[l]; a1 += xp[l + 64]; a2 += xp[l + 128];
      f32x4* op = (f32x4*)(hout + (size_t)r * D_MODEL);
      op[l] = a0; op[l + 64] = a1; op[l + 128] = a2;
      s0 += a0; s1 += a1; s2 += a2;
    }
  }

  if (MODE == 1) {
#pragma unroll
    for (int c = 0; c < 4; ++c) {
      atomicAdd(&cs[4 * l + c],       s0[c]);
      atomicAdd(&cs[256 + 4 * l + c], s1[c]);
      atomicAdd(&cs[512 + 4 * l + c], s2[c]);
    }
    __syncthreads();
    atomicAdd(&colsum[t],       cs[t]);
    atomicAdd(&colsum[t + 256], cs[t + 256]);
    atomicAdd(&colsum[t + 512], cs[t + 512]);
  }
}

// ---- final: out = (colsum/N) @ Wl + bl ----
__global__ void k_final(const float* __restrict__ colsum, const float* __restrict__ Wl,
                        const float* __restrict__ bl, float* __restrict__ out) {
  int j = blockIdx.x * 128 + threadIdx.x;
  if (j >= D_MODEL) return;
  float s = 0.f;
  for (int k = 0; k < D_MODEL; ++k)
    s += colsum[k] * Wl[(size_t)k * D_MODEL + j];
  out[j] = s * (1.0f / (float)N_NODES) + bl[j];
}

extern "C" void kernel_launch(void* const* d_in, const int* in_sizes, int n_in,
                              void* d_out, int out_size, void* d_ws, size_t ws_size,
                              hipStream_t stream) {
  const float* x      = (const float*)d_in[0];
  const unsigned* edg = (const unsigned*)d_in[1];
  const float* W1 = (const float*)d_in[2];
  const float* b1 = (const float*)d_in[3];
  const float* W2 = (const float*)d_in[4];
  const float* b2 = (const float*)d_in[5];
  const float* W3 = (const float*)d_in[6];
  const float* b3 = (const float*)d_in[7];
  const float* Wl = (const float*)d_in[8];
  const float* bl = (const float*)d_in[9];

  float* hout = (float*)d_out;
  float* oout = hout + (size_t)N_NODES * D_MODEL;

  char* ws = (char*)d_ws;
  size_t off = 0;
  float* tmp = (float*)(ws + off);       off += (size_t)N_NODES * D_MODEL * 4;  // 153.6 MB
  ushort_t* pa = (ushort_t*)(ws + off);  off += (size_t)M_PAD * D_MODEL * 2;    // 76.9 MB
  ushort_t* pw0 = (ushort_t*)(ws + off); off += (size_t)D_MODEL * D_MODEL * 2;
  ushort_t* pw1 = (ushort_t*)(ws + off); off += (size_t)D_MODEL * D_MODEL * 2;
  ushort_t* pw2 = (ushort_t*)(ws + off); off += (size_t)D_MODEL * D_MODEL * 2;
  float* dinv = (float*)(ws + off);      off += 50176 * 4;
  int* counts = (int*)(ws + off);        off += 50176 * 4;
  int* rowptr = (int*)(ws + off);        off += 50304 * 4;
  int* csr = (int*)(ws + off);           off += (size_t)N_EDGES * 4;
  int* bsum = (int*)(ws + off);          off += 256 * 4;
  int* boff = (int*)(ws + off);          off += 256 * 4;
  float* colsum = (float*)(ws + off);    off += 1024;
  int* eflag = (int*)(ws + off);         off += 256;

  // setup (edge structure is static across layers)
  k_detect<<<1, 1, 0, stream>>>(edg, eflag);
  k_init<<<196, 256, 0, stream>>>(counts, colsum);
  k_count<<<391, 256, 0, stream>>>(edg, eflag, counts);
  k_scan1<<<196, 256, 0, stream>>>(counts, rowptr, bsum, dinv);
  k_scan2<<<1, 256, 0, stream>>>(bsum, boff);
  k_scan3<<<196, 256, 0, stream>>>(rowptr, boff, counts);
  k_fill<<<391, 256, 0, stream>>>(edg, eflag, rowptr, counts, csr);
  k_pack_w<<<288, 256, 0, stream>>>(W1, pw0);
  k_pack_w<<<288, 256, 0, stream>>>(W2, pw1);
  k_pack_w<<<288, 256, 0, stream>>>(W3, pw2);

  k_pack_a_f32<<<dim3(MBLOCKS, NKT), 256, 0, stream>>>(x, pa);

  const int NGB = (N_NODES + GROWS - 1) / GROWS;  // 1563
  // layer 1
  k_gemm<<<NWG, 256, 0, stream>>>(pa, pw0, dinv, tmp);
  k_gather<0><<<NGB, 256, 0, stream>>>(rowptr, csr, dinv, b1, tmp, pa,
                                       nullptr, nullptr, nullptr);
  // layer 2
  k_gemm<<<NWG, 256, 0, stream>>>(pa, pw1, dinv, tmp);
  k_gather<0><<<NGB, 256, 0, stream>>>(rowptr, csr, dinv, b2, tmp, pa,
                                       nullptr, nullptr, nullptr);
  // layer 3 (fused relu + residual + colsum)
  k_gemm<<<NWG, 256, 0, stream>>>(pa, pw2, dinv, tmp);
  k_gather<1><<<NGB, 256, 0, stream>>>(rowptr, csr, dinv, b3, tmp, nullptr,
                                       x, hout, colsum);

  k_final<<<6, 128, 0, stream>>>(colsum, Wl, bl, oout);
}

// Round 4
// 678.812 us; speedup vs baseline: 2.2344x; 1.1779x over previous
//
#include <hip/hip_runtime.h>
#include <stdint.h>

#define N_NODES 50000
#define D_MODEL 768
#define N_EDGES 100000
#define BM 128
#define BK 32
#define NKT 24                 /* 768/32 */
#define MBLOCKS 391            /* ceil(50000/128) */
#define M_PAD (MBLOCKS * BM)   /* 50048 */
#define NCB 6                  /* 768/128 */
#define TILE_BYTES 8192        /* 128*32*2 */
#define TILE_ELEMS 4096
#define NWG (MBLOCKS * NCB)    /* 2346 */
#define GROWS 32

typedef unsigned short ushort_t;
typedef __bf16 bf16x8 __attribute__((ext_vector_type(8)));
typedef float f32x4 __attribute__((ext_vector_type(4)));

__device__ __forceinline__ unsigned short f2bf(float f) {
  union { float f; unsigned u; } v; v.f = f;
  unsigned r = v.u + 0x7fffu + ((v.u >> 16) & 1u);
  return (unsigned short)(r >> 16);
}

__device__ __forceinline__ uint2 pack4(f32x4 v) {
  uint2 p;
  p.x = (unsigned)f2bf(v[0]) | ((unsigned)f2bf(v[1]) << 16);
  p.y = (unsigned)f2bf(v[2]) | ((unsigned)f2bf(v[3]) << 16);
  return p;
}

__device__ __forceinline__ f32x4 unp4(uint2 p) {
  union { unsigned u; float f; } c;
  f32x4 v;
  c.u = p.x << 16;          v[0] = c.f;
  c.u = p.x & 0xffff0000u;  v[1] = c.f;
  c.u = p.y << 16;          v[2] = c.f;
  c.u = p.y & 0xffff0000u;  v[3] = c.f;
  return v;
}

__device__ __forceinline__ f32x4 relu4(f32x4 v) {
#pragma unroll
  for (int c = 0; c < 4; ++c) v[c] = fmaxf(v[c], 0.f);
  return v;
}

__device__ __forceinline__ void gload_lds16(const void* g, void* l) {
  __builtin_amdgcn_global_load_lds(
      (const __attribute__((address_space(1))) unsigned int*)g,
      (__attribute__((address_space(3))) unsigned int*)l, 16, 0, 0);
}

// ---- edge-index dtype detection (int32 vs int64) ----
__global__ void k_detect(const unsigned* __restrict__ e, int* flag) {
  int is64 = 1;
  for (int i = 0; i < 64; ++i)
    if (e[2 * i + 1] != 0u) { is64 = 0; break; }
  *flag = is64;
}

__device__ __forceinline__ int eidx(const unsigned* e, int logical, int is64) {
  return is64 ? (int)e[2 * logical] : (int)e[logical];
}

// ---- init: zero in-degree counts + colsum ----
__global__ void k_init(int* counts, float* colsum) {
  int i = blockIdx.x * 256 + threadIdx.x;
  if (i < N_NODES) counts[i] = 0;
  if (i < D_MODEL) colsum[i] = 0.0f;
}

__global__ void k_count(const unsigned* __restrict__ e, const int* __restrict__ eflag,
                        int* counts) {
  int i = blockIdx.x * 256 + threadIdx.x;
  if (i >= N_EDGES) return;
  int is64 = *eflag;
  int d = eidx(e, N_EDGES + i, is64);
  atomicAdd(&counts[d], 1);
}

// ---- CSR build: 3-phase exclusive scan of counts -> rowptr, then fill ----
__global__ void k_scan1(const int* __restrict__ counts, int* rowptr, int* bsum,
                        float* dinv) {
  __shared__ int sm[256];
  int b = blockIdx.x, t = threadIdx.x;
  int i = b * 256 + t;
  int v = (i < N_NODES) ? counts[i] : 0;
  if (i < N_NODES) dinv[i] = rsqrtf((float)(v + 1));  // deg = 1 + indeg
  sm[t] = v;
  __syncthreads();
#pragma unroll
  for (int off = 1; off < 256; off <<= 1) {
    int x = (t >= off) ? sm[t - off] : 0;
    __syncthreads();
    sm[t] += x;
    __syncthreads();
  }
  if (i < N_NODES) rowptr[i] = sm[t] - v;   // exclusive
  if (t == 255) bsum[b] = sm[255];
}

__global__ void k_scan2(int* bsum, int* boff) {
  __shared__ int sm[256];
  int t = threadIdx.x;
  int v = (t < 196) ? bsum[t] : 0;
  sm[t] = v;
  __syncthreads();
#pragma unroll
  for (int off = 1; off < 256; off <<= 1) {
    int x = (t >= off) ? sm[t - off] : 0;
    __syncthreads();
    sm[t] += x;
    __syncthreads();
  }
  boff[t] = sm[t] - v;  // exclusive
}

__global__ void k_scan3(int* rowptr, const int* __restrict__ boff, int* counts) {
  int b = blockIdx.x, t = threadIdx.x;
  int i = b * 256 + t;
  if (i < N_NODES) {
    rowptr[i] += boff[b];
    counts[i] = 0;       // reuse as fill cursor
  }
  if (i == 0) rowptr[N_NODES] = N_EDGES;
}

__global__ void k_fill(const unsigned* __restrict__ e, const int* __restrict__ eflag,
                       const int* __restrict__ rowptr, int* counts, int* csr) {
  int i = blockIdx.x * 256 + threadIdx.x;
  if (i >= N_EDGES) return;
  int is64 = *eflag;
  int s = eidx(e, i, is64);
  int d = eidx(e, N_EDGES + i, is64);
  int pos = atomicAdd(&counts[d], 1);
  csr[rowptr[d] + pos] = s;
}

// ---- pack W (f32 [768][768] row-major -> bf16 fragment-major tiles) ----
__global__ void k_pack_w(const float* __restrict__ W, ushort_t* __restrict__ pw) {
  int u = blockIdx.x * 256 + threadIdx.x;   // 73728 units
  if (u >= 6 * 24 * 8 * 64) return;
  int c    = u & 15;
  int g    = (u >> 4) & 3;
  int cb16 = (u >> 6) & 7;
  int kt   = (u >> 9) % NKT;
  int cb   = u / (512 * NKT);
  int col  = cb * 128 + cb16 * 16 + c;
  ushort_t o[8];
#pragma unroll
  for (int j = 0; j < 8; ++j) {
    int k = kt * 32 + g * 4 + (j & 3) + 16 * (j >> 2);
    o[j] = f2bf(W[(size_t)k * D_MODEL + col]);
  }
  uint2 w0, w1;
  w0.x = (unsigned)o[0] | ((unsigned)o[1] << 16);
  w0.y = (unsigned)o[2] | ((unsigned)o[3] << 16);
  w1.x = (unsigned)o[4] | ((unsigned)o[5] << 16);
  w1.y = (unsigned)o[6] | ((unsigned)o[7] << 16);
  uint2* dst = (uint2*)(pw + (size_t)u * 8);
  dst[0] = w0; dst[1] = w1;
}

// ---- pack A for layer 1 (x f32 [N][768] -> bf16 fragment-major tiles) ----
__global__ void k_pack_a_f32(const float* __restrict__ X, ushort_t* __restrict__ pa) {
  __shared__ __align__(16) ushort_t sm[BM * BK];  // 8KB
  int bm = blockIdx.x, kt = blockIdx.y;
  int t = threadIdx.x;
#pragma unroll
  for (int i = 0; i < 4; ++i) {
    int idx = i * 256 + t;        // 0..1023 float4 units
    int row_l = idx >> 3;
    int q = idx & 7;              // which float4 in the 32-k row
    int row = bm * BM + row_l;
    float4 v = make_float4(0.f, 0.f, 0.f, 0.f);
    if (row < N_NODES)
      v = *(const float4*)(X + (size_t)row * D_MODEL + kt * 32 + q * 4);
    uint2 p;
    p.x = (unsigned)f2bf(v.x) | ((unsigned)f2bf(v.y) << 16);
    p.y = (unsigned)f2bf(v.z) | ((unsigned)f2bf(v.w) << 16);
    int off = (row_l >> 4) * 512 + (q & 3) * 128 + (row_l & 15) * 8 + (q >> 2) * 4;
    *(uint2*)(sm + off) = p;
  }
  __syncthreads();
  const uint4* s4 = (const uint4*)sm;           // 512 units
  uint4* d4 = (uint4*)pa + ((size_t)bm * NKT + kt) * 512;
  d4[t] = s4[t];
  d4[t + 256] = s4[t + 256];
}

// ---- GEMM: tmp'[row] = bf16( (A@W)[row] * dinv[row] ) ----
__global__ __launch_bounds__(256) void k_gemm(
    const ushort_t* __restrict__ pa, const ushort_t* __restrict__ pw,
    const float* __restrict__ dinv, ushort_t* __restrict__ tmp) {
  __shared__ __align__(16) char smem[2 * TILE_BYTES];  // A @0, B @8192
  const int qq = NWG / 8, rm = NWG % 8;
  int orig = blockIdx.x;
  int xcd = orig & 7, idx = orig >> 3;
  int wgid = (xcd < rm ? xcd * (qq + 1) : rm * (qq + 1) + (xcd - rm) * qq) + idx;
  int bm = wgid / NCB, cb = wgid % NCB;

  int t = threadIdx.x, w = t >> 6, l = t & 63;
  int wm = w >> 1, wn = w & 1;
  int g = l >> 4, r16 = l & 15;

  f32x4 acc[4][4] = {};

  const char* paT = (const char*)pa + (size_t)bm * NKT * TILE_BYTES;
  const char* pwT = (const char*)pw + (size_t)cb * NKT * TILE_BYTES;

  for (int kt = 0; kt < NKT; ++kt) {
    const char* ga = paT + (size_t)kt * TILE_BYTES;
    const char* gb = pwT + (size_t)kt * TILE_BYTES;
    int u = w * 2;
    gload_lds16(ga + (size_t)u * 1024 + (size_t)l * 16,       &smem[u * 1024]);
    gload_lds16(ga + (size_t)(u + 1) * 1024 + (size_t)l * 16, &smem[(u + 1) * 1024]);
    gload_lds16(gb + (size_t)u * 1024 + (size_t)l * 16,       &smem[TILE_BYTES + u * 1024]);
    gload_lds16(gb + (size_t)(u + 1) * 1024 + (size_t)l * 16, &smem[TILE_BYTES + (u + 1) * 1024]);
    __builtin_amdgcn_s_waitcnt(0);
    __syncthreads();

    bf16x8 af[4], bfr[4];
#pragma unroll
    for (int m = 0; m < 4; ++m)
      af[m] = *(const bf16x8*)&smem[(wm * 4 + m) * 1024 + g * 256 + r16 * 16];
#pragma unroll
    for (int n = 0; n < 4; ++n)
      bfr[n] = *(const bf16x8*)&smem[TILE_BYTES + (wn * 4 + n) * 1024 + g * 256 + r16 * 16];
#pragma unroll
    for (int m = 0; m < 4; ++m)
#pragma unroll
      for (int n = 0; n < 4; ++n)
        acc[m][n] = __builtin_amdgcn_mfma_f32_16x16x32_bf16(af[m], bfr[n], acc[m][n], 0, 0, 0);
    __syncthreads();
  }

  int colb = cb * 128 + wn * 64;
#pragma unroll
  for (int m = 0; m < 4; ++m) {
#pragma unroll
    for (int reg = 0; reg < 4; ++reg) {
      int row = bm * BM + wm * 64 + m * 16 + g * 4 + reg;
      if (row >= N_NODES) continue;
      float di = dinv[row];
      size_t base = (size_t)row * D_MODEL + colb;
#pragma unroll
      for (int n = 0; n < 4; ++n)
        tmp[base + n * 16 + r16] = f2bf(acc[m][n][reg] * di);
    }
  }
}

// ---- gather ----
// MODE 0 (layers 1,2): pa[r] = relu(dinv[r]*(tmp'[r]+sum_in tmp'[s]) + bias),
//                      written bf16 directly in MFMA-fragment-packed layout.
// MODE 1 (layer 3):    hout[r] = relu(...) + x[r] (f32), plus colsum reduce.
template <int MODE>
__global__ __launch_bounds__(256) void k_gather(
    const int* __restrict__ rowptr, const int* __restrict__ csr,
    const float* __restrict__ dinv, const float* __restrict__ bias,
    const ushort_t* __restrict__ tmp, ushort_t* __restrict__ pa,
    const float* __restrict__ x, float* __restrict__ hout,
    float* __restrict__ colsum) {
  __shared__ float cs[768];
  int t = threadIdx.x;
  if (MODE == 1) {
    cs[t] = 0.f; cs[t + 256] = 0.f; cs[t + 512] = 0.f;
    __syncthreads();
  }
  int w = t >> 6, l = t & 63;
  const f32x4* b4 = (const f32x4*)bias;
  f32x4 bb0 = b4[l], bb1 = b4[l + 64], bb2 = b4[l + 128];
  f32x4 s0 = {0.f, 0.f, 0.f, 0.f}, s1 = s0, s2 = s0;
  int kt0 = l >> 3, q = l & 7;
  int qoff = (q & 3) * 128 + (q >> 2) * 4;

  for (int rr = w; rr < GROWS; rr += 4) {
    int r = blockIdx.x * GROWS + rr;
    if (r >= N_NODES) break;
    const uint2* rp = (const uint2*)(tmp + (size_t)r * D_MODEL);
    f32x4 a0 = unp4(rp[l]), a1 = unp4(rp[l + 64]), a2 = unp4(rp[l + 128]);
    int beg = rowptr[r], end = rowptr[r + 1];
    int j = beg;
    for (; j + 2 <= end; j += 2) {
      int sa = csr[j], sb = csr[j + 1];
      const uint2* pA = (const uint2*)(tmp + (size_t)sa * D_MODEL);
      const uint2* pB = (const uint2*)(tmp + (size_t)sb * D_MODEL);
      uint2 va0 = pA[l], va1 = pA[l + 64], va2 = pA[l + 128];
      uint2 vb0 = pB[l], vb1 = pB[l + 64], vb2 = pB[l + 128];
      a0 += unp4(va0) + unp4(vb0);
      a1 += unp4(va1) + unp4(vb1);
      a2 += unp4(va2) + unp4(vb2);
    }
    if (j < end) {
      int s = csr[j];
      const uint2* sp = (const uint2*)(tmp + (size_t)s * D_MODEL);
      a0 += unp4(sp[l]); a1 += unp4(sp[l + 64]); a2 += unp4(sp[l + 128]);
    }
    float di = dinv[r];
    a0 = relu4(a0 * di + bb0);
    a1 = relu4(a1 * di + bb1);
    a2 = relu4(a2 * di + bb2);
    if (MODE == 0) {
      int bm = r >> 7, row_l = r & 127;
      size_t tb = ((size_t)bm * NKT + kt0) * TILE_ELEMS +
                  (row_l >> 4) * 512 + (row_l & 15) * 8 + qoff;
      *(uint2*)(pa + tb)                   = pack4(a0);
      *(uint2*)(pa + tb + 8 * TILE_ELEMS)  = pack4(a1);
      *(uint2*)(pa + tb + 16 * TILE_ELEMS) = pack4(a2);
    } else {
      const f32x4* xp = (const f32x4*)(x + (size_t)r * D_MODEL);
      a0 += xp[l]; a1 += xp[l + 64]; a2 += xp[l + 128];
      f32x4* op = (f32x4*)(hout + (size_t)r * D_MODEL);
      op[l] = a0; op[l + 64] = a1; op[l + 128] = a2;
      s0 += a0; s1 += a1; s2 += a2;
    }
  }

  if (MODE == 1) {
#pragma unroll
    for (int c = 0; c < 4; ++c) {
      atomicAdd(&cs[4 * l + c],       s0[c]);
      atomicAdd(&cs[256 + 4 * l + c], s1[c]);
      atomicAdd(&cs[512 + 4 * l + c], s2[c]);
    }
    __syncthreads();
    atomicAdd(&colsum[t],       cs[t]);
    atomicAdd(&colsum[t + 256], cs[t + 256]);
    atomicAdd(&colsum[t + 512], cs[t + 512]);
  }
}

// ---- final: out = (colsum/N) @ Wl + bl ----
__global__ void k_final(const float* __restrict__ colsum, const float* __restrict__ Wl,
                        const float* __restrict__ bl, float* __restrict__ out) {
  int j = blockIdx.x * 128 + threadIdx.x;
  if (j >= D_MODEL) return;
  float s = 0.f;
  for (int k = 0; k < D_MODEL; ++k)
    s += colsum[k] * Wl[(size_t)k * D_MODEL + j];
  out[j] = s * (1.0f / (float)N_NODES) + bl[j];
}

extern "C" void kernel_launch(void* const* d_in, const int* in_sizes, int n_in,
                              void* d_out, int out_size, void* d_ws, size_t ws_size,
                              hipStream_t stream) {
  const float* x      = (const float*)d_in[0];
  const unsigned* edg = (const unsigned*)d_in[1];
  const float* W1 = (const float*)d_in[2];
  const float* b1 = (const float*)d_in[3];
  const float* W2 = (const float*)d_in[4];
  const float* b2 = (const float*)d_in[5];
  const float* W3 = (const float*)d_in[6];
  const float* b3 = (const float*)d_in[7];
  const float* Wl = (const float*)d_in[8];
  const float* bl = (const float*)d_in[9];

  float* hout = (float*)d_out;
  float* oout = hout + (size_t)N_NODES * D_MODEL;

  char* ws = (char*)d_ws;
  size_t off = 0;
  ushort_t* tmp = (ushort_t*)(ws + off); off += (size_t)N_NODES * D_MODEL * 2;  // 76.8 MB
  ushort_t* pa = (ushort_t*)(ws + off);  off += (size_t)M_PAD * D_MODEL * 2;    // 76.9 MB
  ushort_t* pw0 = (ushort_t*)(ws + off); off += (size_t)D_MODEL * D_MODEL * 2;
  ushort_t* pw1 = (ushort_t*)(ws + off); off += (size_t)D_MODEL * D_MODEL * 2;
  ushort_t* pw2 = (ushort_t*)(ws + off); off += (size_t)D_MODEL * D_MODEL * 2;
  float* dinv = (float*)(ws + off);      off += 50176 * 4;
  int* counts = (int*)(ws + off);        off += 50176 * 4;
  int* rowptr = (int*)(ws + off);        off += 50304 * 4;
  int* csr = (int*)(ws + off);           off += (size_t)N_EDGES * 4;
  int* bsum = (int*)(ws + off);          off += 256 * 4;
  int* boff = (int*)(ws + off);          off += 256 * 4;
  float* colsum = (float*)(ws + off);    off += 1024;
  int* eflag = (int*)(ws + off);         off += 256;

  // setup (edge structure is static across layers)
  k_detect<<<1, 1, 0, stream>>>(edg, eflag);
  k_init<<<196, 256, 0, stream>>>(counts, colsum);
  k_count<<<391, 256, 0, stream>>>(edg, eflag, counts);
  k_scan1<<<196, 256, 0, stream>>>(counts, rowptr, bsum, dinv);
  k_scan2<<<1, 256, 0, stream>>>(bsum, boff);
  k_scan3<<<196, 256, 0, stream>>>(rowptr, boff, counts);
  k_fill<<<391, 256, 0, stream>>>(edg, eflag, rowptr, counts, csr);
  k_pack_w<<<288, 256, 0, stream>>>(W1, pw0);
  k_pack_w<<<288, 256, 0, stream>>>(W2, pw1);
  k_pack_w<<<288, 256, 0, stream>>>(W3, pw2);

  k_pack_a_f32<<<dim3(MBLOCKS, NKT), 256, 0, stream>>>(x, pa);

  const int NGB = (N_NODES + GROWS - 1) / GROWS;  // 1563
  // layer 1
  k_gemm<<<NWG, 256, 0, stream>>>(pa, pw0, dinv, tmp);
  k_gather<0><<<NGB, 256, 0, stream>>>(rowptr, csr, dinv, b1, tmp, pa,
                                       nullptr, nullptr, nullptr);
  // layer 2
  k_gemm<<<NWG, 256, 0, stream>>>(pa, pw1, dinv, tmp);
  k_gather<0><<<NGB, 256, 0, stream>>>(rowptr, csr, dinv, b2, tmp, pa,
                                       nullptr, nullptr, nullptr);
  // layer 3 (fused relu + residual + colsum)
  k_gemm<<<NWG, 256, 0, stream>>>(pa, pw2, dinv, tmp);
  k_gather<1><<<NGB, 256, 0, stream>>>(rowptr, csr, dinv, b3, tmp, nullptr,
                                       x, hout, colsum);

  k_final<<<6, 128, 0, stream>>>(colsum, Wl, bl, oout);
}

// Round 5
// 636.950 us; speedup vs baseline: 2.3813x; 1.0657x over previous
//
#include <hip/hip_runtime.h>
#include <stdint.h>

#define N_NODES 50000
#define D_MODEL 768
#define N_EDGES 100000
#define BM 128
#define BK 32
#define NKT 24                 /* 768/32 */
#define MBLOCKS 391            /* ceil(50000/128) */
#define M_PAD (MBLOCKS * BM)   /* 50048 */
#define NCB 6                  /* 768/128 */
#define TILE_BYTES 8192        /* 128*32*2 */
#define TILE_ELEMS 4096
#define NWG (MBLOCKS * NCB)    /* 2346 */
#define GROWS 16               /* 50000 % 16 == 0 -> no row guards */

typedef unsigned short ushort_t;
typedef __bf16 bf16x8 __attribute__((ext_vector_type(8)));
typedef float f32x4 __attribute__((ext_vector_type(4)));

__device__ __forceinline__ unsigned short f2bf(float f) {
  union { float f; unsigned u; } v; v.f = f;
  unsigned r = v.u + 0x7fffu + ((v.u >> 16) & 1u);
  return (unsigned short)(r >> 16);
}

__device__ __forceinline__ uint2 pack4(f32x4 v) {
  uint2 p;
  p.x = (unsigned)f2bf(v[0]) | ((unsigned)f2bf(v[1]) << 16);
  p.y = (unsigned)f2bf(v[2]) | ((unsigned)f2bf(v[3]) << 16);
  return p;
}

__device__ __forceinline__ f32x4 unp4(uint2 p) {
  union { unsigned u; float f; } c;
  f32x4 v;
  c.u = p.x << 16;          v[0] = c.f;
  c.u = p.x & 0xffff0000u;  v[1] = c.f;
  c.u = p.y << 16;          v[2] = c.f;
  c.u = p.y & 0xffff0000u;  v[3] = c.f;
  return v;
}

__device__ __forceinline__ f32x4 relu4(f32x4 v) {
#pragma unroll
  for (int c = 0; c < 4; ++c) v[c] = fmaxf(v[c], 0.f);
  return v;
}

__device__ __forceinline__ void gload_lds16(const void* g, void* l) {
  __builtin_amdgcn_global_load_lds(
      (const __attribute__((address_space(1))) unsigned int*)g,
      (__attribute__((address_space(3))) unsigned int*)l, 16, 0, 0);
}

// ---- edge-index dtype detection (int32 vs int64) ----
__global__ void k_detect(const unsigned* __restrict__ e, int* flag) {
  int is64 = 1;
  for (int i = 0; i < 64; ++i)
    if (e[2 * i + 1] != 0u) { is64 = 0; break; }
  *flag = is64;
}

__device__ __forceinline__ int eidx(const unsigned* e, int logical, int is64) {
  return is64 ? (int)e[2 * logical] : (int)e[logical];
}

// ---- init: zero in-degree counts + colsum ----
__global__ void k_init(int* counts, float* colsum) {
  int i = blockIdx.x * 256 + threadIdx.x;
  if (i < N_NODES) counts[i] = 0;
  if (i < D_MODEL) colsum[i] = 0.0f;
}

__global__ void k_count(const unsigned* __restrict__ e, const int* __restrict__ eflag,
                        int* counts) {
  int i = blockIdx.x * 256 + threadIdx.x;
  if (i >= N_EDGES) return;
  int is64 = *eflag;
  int d = eidx(e, N_EDGES + i, is64);
  atomicAdd(&counts[d], 1);
}

// ---- CSR build: 3-phase exclusive scan of counts -> rowptr, then fill ----
__global__ void k_scan1(const int* __restrict__ counts, int* rowptr, int* bsum,
                        float* dinv) {
  __shared__ int sm[256];
  int b = blockIdx.x, t = threadIdx.x;
  int i = b * 256 + t;
  int v = (i < N_NODES) ? counts[i] : 0;
  if (i < N_NODES) dinv[i] = rsqrtf((float)(v + 1));  // deg = 1 + indeg
  sm[t] = v;
  __syncthreads();
#pragma unroll
  for (int off = 1; off < 256; off <<= 1) {
    int x = (t >= off) ? sm[t - off] : 0;
    __syncthreads();
    sm[t] += x;
    __syncthreads();
  }
  if (i < N_NODES) rowptr[i] = sm[t] - v;   // exclusive
  if (t == 255) bsum[b] = sm[255];
}

__global__ void k_scan2(int* bsum, int* boff) {
  __shared__ int sm[256];
  int t = threadIdx.x;
  int v = (t < 196) ? bsum[t] : 0;
  sm[t] = v;
  __syncthreads();
#pragma unroll
  for (int off = 1; off < 256; off <<= 1) {
    int x = (t >= off) ? sm[t - off] : 0;
    __syncthreads();
    sm[t] += x;
    __syncthreads();
  }
  boff[t] = sm[t] - v;  // exclusive
}

__global__ void k_scan3(int* rowptr, const int* __restrict__ boff, int* counts) {
  int b = blockIdx.x, t = threadIdx.x;
  int i = b * 256 + t;
  if (i < N_NODES) {
    rowptr[i] += boff[b];
    counts[i] = 0;       // reuse as fill cursor
  }
  if (i == 0) rowptr[N_NODES] = N_EDGES;
}

__global__ void k_fill(const unsigned* __restrict__ e, const int* __restrict__ eflag,
                       const int* __restrict__ rowptr, int* counts, int* csr) {
  int i = blockIdx.x * 256 + threadIdx.x;
  if (i >= N_EDGES) return;
  int is64 = *eflag;
  int s = eidx(e, i, is64);
  int d = eidx(e, N_EDGES + i, is64);
  int pos = atomicAdd(&counts[d], 1);
  csr[rowptr[d] + pos] = s;
}

// ---- pack W (f32 [768][768] row-major -> bf16 fragment-major tiles) ----
__global__ void k_pack_w(const float* __restrict__ W, ushort_t* __restrict__ pw) {
  int u = blockIdx.x * 256 + threadIdx.x;   // 73728 units
  if (u >= 6 * 24 * 8 * 64) return;
  int c    = u & 15;
  int g    = (u >> 4) & 3;
  int cb16 = (u >> 6) & 7;
  int kt   = (u >> 9) % NKT;
  int cb   = u / (512 * NKT);
  int col  = cb * 128 + cb16 * 16 + c;
  ushort_t o[8];
#pragma unroll
  for (int j = 0; j < 8; ++j) {
    int k = kt * 32 + g * 4 + (j & 3) + 16 * (j >> 2);
    o[j] = f2bf(W[(size_t)k * D_MODEL + col]);
  }
  uint2 w0, w1;
  w0.x = (unsigned)o[0] | ((unsigned)o[1] << 16);
  w0.y = (unsigned)o[2] | ((unsigned)o[3] << 16);
  w1.x = (unsigned)o[4] | ((unsigned)o[5] << 16);
  w1.y = (unsigned)o[6] | ((unsigned)o[7] << 16);
  uint2* dst = (uint2*)(pw + (size_t)u * 8);
  dst[0] = w0; dst[1] = w1;
}

// ---- pack A for layer 1 (x f32 [N][768] -> bf16 fragment-major tiles) ----
__global__ void k_pack_a_f32(const float* __restrict__ X, ushort_t* __restrict__ pa) {
  __shared__ __align__(16) ushort_t sm[BM * BK];  // 8KB
  int bm = blockIdx.x, kt = blockIdx.y;
  int t = threadIdx.x;
#pragma unroll
  for (int i = 0; i < 4; ++i) {
    int idx = i * 256 + t;        // 0..1023 float4 units
    int row_l = idx >> 3;
    int q = idx & 7;              // which float4 in the 32-k row
    int row = bm * BM + row_l;
    float4 v = make_float4(0.f, 0.f, 0.f, 0.f);
    if (row < N_NODES)
      v = *(const float4*)(X + (size_t)row * D_MODEL + kt * 32 + q * 4);
    uint2 p;
    p.x = (unsigned)f2bf(v.x) | ((unsigned)f2bf(v.y) << 16);
    p.y = (unsigned)f2bf(v.z) | ((unsigned)f2bf(v.w) << 16);
    int off = (row_l >> 4) * 512 + (q & 3) * 128 + (row_l & 15) * 8 + (q >> 2) * 4;
    *(uint2*)(sm + off) = p;
  }
  __syncthreads();
  const uint4* s4 = (const uint4*)sm;           // 512 units
  uint4* d4 = (uint4*)pa + ((size_t)bm * NKT + kt) * 512;
  d4[t] = s4[t];
  d4[t + 256] = s4[t + 256];
}

// ---- GEMM: tmp'[row] = bf16( (A@W)[row] * dinv[row] ) ----
__global__ __launch_bounds__(256) void k_gemm(
    const ushort_t* __restrict__ pa, const ushort_t* __restrict__ pw,
    const float* __restrict__ dinv, ushort_t* __restrict__ tmp) {
  __shared__ __align__(16) char smem[2 * TILE_BYTES];  // A @0, B @8192
  const int qq = NWG / 8, rm = NWG % 8;
  int orig = blockIdx.x;
  int xcd = orig & 7, idx = orig >> 3;
  int wgid = (xcd < rm ? xcd * (qq + 1) : rm * (qq + 1) + (xcd - rm) * qq) + idx;
  int bm = wgid / NCB, cb = wgid % NCB;

  int t = threadIdx.x, w = t >> 6, l = t & 63;
  int wm = w >> 1, wn = w & 1;
  int g = l >> 4, r16 = l & 15;

  f32x4 acc[4][4] = {};

  const char* paT = (const char*)pa + (size_t)bm * NKT * TILE_BYTES;
  const char* pwT = (const char*)pw + (size_t)cb * NKT * TILE_BYTES;

  for (int kt = 0; kt < NKT; ++kt) {
    const char* ga = paT + (size_t)kt * TILE_BYTES;
    const char* gb = pwT + (size_t)kt * TILE_BYTES;
    int u = w * 2;
    gload_lds16(ga + (size_t)u * 1024 + (size_t)l * 16,       &smem[u * 1024]);
    gload_lds16(ga + (size_t)(u + 1) * 1024 + (size_t)l * 16, &smem[(u + 1) * 1024]);
    gload_lds16(gb + (size_t)u * 1024 + (size_t)l * 16,       &smem[TILE_BYTES + u * 1024]);
    gload_lds16(gb + (size_t)(u + 1) * 1024 + (size_t)l * 16, &smem[TILE_BYTES + (u + 1) * 1024]);
    __builtin_amdgcn_s_waitcnt(0);
    __syncthreads();

    bf16x8 af[4], bfr[4];
#pragma unroll
    for (int m = 0; m < 4; ++m)
      af[m] = *(const bf16x8*)&smem[(wm * 4 + m) * 1024 + g * 256 + r16 * 16];
#pragma unroll
    for (int n = 0; n < 4; ++n)
      bfr[n] = *(const bf16x8*)&smem[TILE_BYTES + (wn * 4 + n) * 1024 + g * 256 + r16 * 16];
#pragma unroll
    for (int m = 0; m < 4; ++m)
#pragma unroll
      for (int n = 0; n < 4; ++n)
        acc[m][n] = __builtin_amdgcn_mfma_f32_16x16x32_bf16(af[m], bfr[n], acc[m][n], 0, 0, 0);
    __syncthreads();
  }

  int colb = cb * 128 + wn * 64;
#pragma unroll
  for (int m = 0; m < 4; ++m) {
#pragma unroll
    for (int reg = 0; reg < 4; ++reg) {
      int row = bm * BM + wm * 64 + m * 16 + g * 4 + reg;
      if (row >= N_NODES) continue;
      float di = dinv[row];
      size_t base = (size_t)row * D_MODEL + colb;
#pragma unroll
      for (int n = 0; n < 4; ++n)
        tmp[base + n * 16 + r16] = f2bf(acc[m][n][reg] * di);
    }
  }
}

// ---- gather ----
// MODE 0 (layers 1,2): pa[r] = relu(dinv[r]*(tmp'[r]+sum_in tmp'[s]) + bias),
//   staged in LDS (packed-tile image, bank-swizzled), then written as 24
//   contiguous 1KB chunks (full-line writes, no amplification).
// MODE 1 (layer 3): hout[r] = relu(...) + x[r] (f32), plus colsum reduce.
// Two rows per wave processed concurrently (independent load chains).
template <int MODE>
__global__ __launch_bounds__(256) void k_gather(
    const int* __restrict__ rowptr, const int* __restrict__ csr,
    const float* __restrict__ dinv, const float* __restrict__ bias,
    const ushort_t* __restrict__ tmp, ushort_t* __restrict__ pa,
    const float* __restrict__ x, float* __restrict__ hout,
    float* __restrict__ colsum) {
  __shared__ __align__(16) char sraw[MODE == 0 ? GROWS * D_MODEL * 2 : 3072];
  __shared__ int srp[GROWS + 1];
  int t = threadIdx.x;
  int r0 = blockIdx.x * GROWS;
  if (t <= GROWS) srp[t] = rowptr[r0 + t];
  float* cs = (float*)sraw;
  if (MODE == 1) {
    cs[t] = 0.f; cs[t + 256] = 0.f; cs[t + 512] = 0.f;
  }
  __syncthreads();

  int w = t >> 6, l = t & 63;
  const f32x4* b4 = (const f32x4*)bias;
  f32x4 bb0 = b4[l], bb1 = b4[l + 64], bb2 = b4[l + 128];
  f32x4 s0 = {0.f, 0.f, 0.f, 0.f}, s1 = s0, s2 = s0;
  int kt0 = l >> 3, q = l & 7;
  // LDS byte offset pieces for packed image (MODE 0)
  int qoffB = (q & 3) * 256 + (q >> 2) * 8;
  int swz = (kt0 & 7) << 4;

  for (int p = w; p < GROWS / 2; p += 4) {     // 2 pairs per wave
    int iA = p, iB = p + GROWS / 2;
    int rA = r0 + iA, rB = r0 + iB;
    const uint2* rpA = (const uint2*)(tmp + (size_t)rA * D_MODEL);
    const uint2* rpB = (const uint2*)(tmp + (size_t)rB * D_MODEL);
    f32x4 a0 = unp4(rpA[l]), a1 = unp4(rpA[l + 64]), a2 = unp4(rpA[l + 128]);
    f32x4 c0 = unp4(rpB[l]), c1 = unp4(rpB[l + 64]), c2 = unp4(rpB[l + 128]);
    int jA = srp[iA], eA = srp[iA + 1];
    int jB = srp[iB], eB = srp[iB + 1];
    while (jA < eA && jB < eB) {
      int sA = csr[jA++], sB = csr[jB++];
      const uint2* pA = (const uint2*)(tmp + (size_t)sA * D_MODEL);
      const uint2* pB = (const uint2*)(tmp + (size_t)sB * D_MODEL);
      uint2 x0 = pA[l], x1 = pA[l + 64], x2 = pA[l + 128];
      uint2 y0 = pB[l], y1 = pB[l + 64], y2 = pB[l + 128];
      a0 += unp4(x0); a1 += unp4(x1); a2 += unp4(x2);
      c0 += unp4(y0); c1 += unp4(y1); c2 += unp4(y2);
    }
    while (jA < eA) {
      int sA = csr[jA++];
      const uint2* pA = (const uint2*)(tmp + (size_t)sA * D_MODEL);
      a0 += unp4(pA[l]); a1 += unp4(pA[l + 64]); a2 += unp4(pA[l + 128]);
    }
    while (jB < eB) {
      int sB = csr[jB++];
      const uint2* pB = (const uint2*)(tmp + (size_t)sB * D_MODEL);
      c0 += unp4(pB[l]); c1 += unp4(pB[l + 64]); c2 += unp4(pB[l + 128]);
    }
    float dA = dinv[rA], dB = dinv[rB];
    a0 = relu4(a0 * dA + bb0); a1 = relu4(a1 * dA + bb1); a2 = relu4(a2 * dA + bb2);
    c0 = relu4(c0 * dB + bb0); c1 = relu4(c1 * dB + bb1); c2 = relu4(c2 * dB + bb2);
    if (MODE == 0) {
      // stage into packed-tile LDS image: [kt(24)][1KB chunk], swizzled
      int baseA = (iA << 4) + qoffB, baseB = (iB << 4) + qoffB;
      char* sA0 = sraw + (((kt0 * 1024) + baseA) ^ swz);
      char* sB0 = sraw + (((kt0 * 1024) + baseB) ^ swz);
      *(uint2*)(sA0)         = pack4(a0);
      *(uint2*)(sA0 + 8192)  = pack4(a1);
      *(uint2*)(sA0 + 16384) = pack4(a2);
      *(uint2*)(sB0)         = pack4(c0);
      *(uint2*)(sB0 + 8192)  = pack4(c1);
      *(uint2*)(sB0 + 16384) = pack4(c2);
    } else {
      const f32x4* xpA = (const f32x4*)(x + (size_t)rA * D_MODEL);
      const f32x4* xpB = (const f32x4*)(x + (size_t)rB * D_MODEL);
      a0 += xpA[l]; a1 += xpA[l + 64]; a2 += xpA[l + 128];
      c0 += xpB[l]; c1 += xpB[l + 64]; c2 += xpB[l + 128];
      f32x4* opA = (f32x4*)(hout + (size_t)rA * D_MODEL);
      f32x4* opB = (f32x4*)(hout + (size_t)rB * D_MODEL);
      opA[l] = a0; opA[l + 64] = a1; opA[l + 128] = a2;
      opB[l] = c0; opB[l + 64] = c1; opB[l + 128] = c2;
      s0 += a0 + c0; s1 += a1 + c1; s2 += a2 + c2;
    }
  }

  if (MODE == 0) {
    __syncthreads();
    // copy LDS image -> pa: 24 chunks of 1KB, contiguous
    int bm = r0 >> 7, rb0 = (r0 >> 4) & 7;
    size_t tilebase = ((size_t)bm * NKT) * TILE_ELEMS + (size_t)rb0 * 512;
#pragma unroll
    for (int it = 0; it < 6; ++it) {
      int byte = (it * 256 + t) * 16;            // 0..24575
      int kt = byte >> 10;
      uint4 v = *(const uint4*)(sraw + (byte ^ ((kt & 7) << 4)));
      *(uint4*)((char*)(pa + tilebase + (size_t)kt * TILE_ELEMS) + (byte & 1023)) = v;
    }
  } else {
#pragma unroll
    for (int c = 0; c < 4; ++c) {
      atomicAdd(&cs[4 * l + c],       s0[c]);
      atomicAdd(&cs[256 + 4 * l + c], s1[c]);
      atomicAdd(&cs[512 + 4 * l + c], s2[c]);
    }
    __syncthreads();
    atomicAdd(&colsum[t],       cs[t]);
    atomicAdd(&colsum[t + 256], cs[t + 256]);
    atomicAdd(&colsum[t + 512], cs[t + 512]);
  }
}

// ---- final: out = (colsum/N) @ Wl + bl ----
__global__ void k_final(const float* __restrict__ colsum, const float* __restrict__ Wl,
                        const float* __restrict__ bl, float* __restrict__ out) {
  int j = blockIdx.x * 128 + threadIdx.x;
  if (j >= D_MODEL) return;
  float s = 0.f;
  for (int k = 0; k < D_MODEL; ++k)
    s += colsum[k] * Wl[(size_t)k * D_MODEL + j];
  out[j] = s * (1.0f / (float)N_NODES) + bl[j];
}

extern "C" void kernel_launch(void* const* d_in, const int* in_sizes, int n_in,
                              void* d_out, int out_size, void* d_ws, size_t ws_size,
                              hipStream_t stream) {
  const float* x      = (const float*)d_in[0];
  const unsigned* edg = (const unsigned*)d_in[1];
  const float* W1 = (const float*)d_in[2];
  const float* b1 = (const float*)d_in[3];
  const float* W2 = (const float*)d_in[4];
  const float* b2 = (const float*)d_in[5];
  const float* W3 = (const float*)d_in[6];
  const float* b3 = (const float*)d_in[7];
  const float* Wl = (const float*)d_in[8];
  const float* bl = (const float*)d_in[9];

  float* hout = (float*)d_out;
  float* oout = hout + (size_t)N_NODES * D_MODEL;

  char* ws = (char*)d_ws;
  size_t off = 0;
  ushort_t* tmp = (ushort_t*)(ws + off); off += (size_t)N_NODES * D_MODEL * 2;  // 76.8 MB
  ushort_t* pa = (ushort_t*)(ws + off);  off += (size_t)M_PAD * D_MODEL * 2;    // 76.9 MB
  ushort_t* pw0 = (ushort_t*)(ws + off); off += (size_t)D_MODEL * D_MODEL * 2;
  ushort_t* pw1 = (ushort_t*)(ws + off); off += (size_t)D_MODEL * D_MODEL * 2;
  ushort_t* pw2 = (ushort_t*)(ws + off); off += (size_t)D_MODEL * D_MODEL * 2;
  float* dinv = (float*)(ws + off);      off += 50176 * 4;
  int* counts = (int*)(ws + off);        off += 50176 * 4;
  int* rowptr = (int*)(ws + off);        off += 50304 * 4;
  int* csr = (int*)(ws + off);           off += (size_t)N_EDGES * 4;
  int* bsum = (int*)(ws + off);          off += 256 * 4;
  int* boff = (int*)(ws + off);          off += 256 * 4;
  float* colsum = (float*)(ws + off);    off += 1024;
  int* eflag = (int*)(ws + off);         off += 256;

  // setup (edge structure is static across layers)
  k_detect<<<1, 1, 0, stream>>>(edg, eflag);
  k_init<<<196, 256, 0, stream>>>(counts, colsum);
  k_count<<<391, 256, 0, stream>>>(edg, eflag, counts);
  k_scan1<<<196, 256, 0, stream>>>(counts, rowptr, bsum, dinv);
  k_scan2<<<1, 256, 0, stream>>>(bsum, boff);
  k_scan3<<<196, 256, 0, stream>>>(rowptr, boff, counts);
  k_fill<<<391, 256, 0, stream>>>(edg, eflag, rowptr, counts, csr);
  k_pack_w<<<288, 256, 0, stream>>>(W1, pw0);
  k_pack_w<<<288, 256, 0, stream>>>(W2, pw1);
  k_pack_w<<<288, 256, 0, stream>>>(W3, pw2);

  k_pack_a_f32<<<dim3(MBLOCKS, NKT), 256, 0, stream>>>(x, pa);

  const int NGB = N_NODES / GROWS;  // 3125
  // layer 1
  k_gemm<<<NWG, 256, 0, stream>>>(pa, pw0, dinv, tmp);
  k_gather<0><<<NGB, 256, 0, stream>>>(rowptr, csr, dinv, b1, tmp, pa,
                                       nullptr, nullptr, nullptr);
  // layer 2
  k_gemm<<<NWG, 256, 0, stream>>>(pa, pw1, dinv, tmp);
  k_gather<0><<<NGB, 256, 0, stream>>>(rowptr, csr, dinv, b2, tmp, pa,
                                       nullptr, nullptr, nullptr);
  // layer 3 (fused relu + residual + colsum)
  k_gemm<<<NWG, 256, 0, stream>>>(pa, pw2, dinv, tmp);
  k_gather<1><<<NGB, 256, 0, stream>>>(rowptr, csr, dinv, b3, tmp, nullptr,
                                       x, hout, colsum);

  k_final<<<6, 128, 0, stream>>>(colsum, Wl, bl, oout);
}

// Round 6
// 603.251 us; speedup vs baseline: 2.5143x; 1.0559x over previous
//
#include <hip/hip_runtime.h>
#include <stdint.h>

#define N_NODES 50000
#define D_MODEL 768
#define N_EDGES 100000
#define BM 128
#define BK 32
#define NKT 24                 /* 768/32 */
#define MBLOCKS 391            /* ceil(50000/128) */
#define M_PAD (MBLOCKS * BM)   /* 50048 */
#define NCB 6                  /* 768/128 */
#define TILE_BYTES 8192        /* 128*32*2 */
#define TILE_ELEMS 4096
#define NWG (MBLOCKS * NCB)    /* 2346 */
#define GROWS0 16              /* MODE-0 gather rows/block (LDS-staged) */
#define GROWS1 32              /* MODE-1 gather rows/block */

typedef unsigned short ushort_t;
typedef __bf16 bf16x8 __attribute__((ext_vector_type(8)));
typedef float f32x4 __attribute__((ext_vector_type(4)));

__device__ __forceinline__ unsigned short f2bf(float f) {
  union { float f; unsigned u; } v; v.f = f;
  unsigned r = v.u + 0x7fffu + ((v.u >> 16) & 1u);
  return (unsigned short)(r >> 16);
}

__device__ __forceinline__ uint2 pack4(f32x4 v) {
  uint2 p;
  p.x = (unsigned)f2bf(v[0]) | ((unsigned)f2bf(v[1]) << 16);
  p.y = (unsigned)f2bf(v[2]) | ((unsigned)f2bf(v[3]) << 16);
  return p;
}

__device__ __forceinline__ f32x4 unp4(uint2 p) {
  union { unsigned u; float f; } c;
  f32x4 v;
  c.u = p.x << 16;          v[0] = c.f;
  c.u = p.x & 0xffff0000u;  v[1] = c.f;
  c.u = p.y << 16;          v[2] = c.f;
  c.u = p.y & 0xffff0000u;  v[3] = c.f;
  return v;
}

__device__ __forceinline__ f32x4 relu4(f32x4 v) {
#pragma unroll
  for (int c = 0; c < 4; ++c) v[c] = fmaxf(v[c], 0.f);
  return v;
}

__device__ __forceinline__ void gload_lds16(const void* g, void* l) {
  __builtin_amdgcn_global_load_lds(
      (const __attribute__((address_space(1))) unsigned int*)g,
      (__attribute__((address_space(3))) unsigned int*)l, 16, 0, 0);
}

__device__ __forceinline__ int eidx(const unsigned* e, int logical, int is64) {
  return is64 ? (int)e[2 * logical] : (int)e[logical];
}

// ---- init: zero counts + colsum; block 0 also does edge-dtype detect ----
__global__ void k_init(const unsigned* __restrict__ e, int* counts, float* colsum,
                       int* eflag) {
  int i = blockIdx.x * 256 + threadIdx.x;
  if (i < N_NODES) counts[i] = 0;
  if (i < D_MODEL) colsum[i] = 0.0f;
  if (i == 0) {
    int is64 = 1;
    for (int k = 0; k < 64; ++k)
      if (e[2 * k + 1] != 0u) { is64 = 0; break; }
    *eflag = is64;
  }
}

__global__ void k_count(const unsigned* __restrict__ e, const int* __restrict__ eflag,
                        int* counts) {
  int i = blockIdx.x * 256 + threadIdx.x;
  if (i >= N_EDGES) return;
  int is64 = *eflag;
  int d = eidx(e, N_EDGES + i, is64);
  atomicAdd(&counts[d], 1);
}

// ---- CSR build: 3-phase exclusive scan of counts -> rowptr, then fill ----
__global__ void k_scan1(const int* __restrict__ counts, int* rowptr, int* bsum,
                        float* dinv) {
  __shared__ int sm[256];
  int b = blockIdx.x, t = threadIdx.x;
  int i = b * 256 + t;
  int v = (i < N_NODES) ? counts[i] : 0;
  if (i < N_NODES) dinv[i] = rsqrtf((float)(v + 1));  // deg = 1 + indeg
  sm[t] = v;
  __syncthreads();
#pragma unroll
  for (int off = 1; off < 256; off <<= 1) {
    int x = (t >= off) ? sm[t - off] : 0;
    __syncthreads();
    sm[t] += x;
    __syncthreads();
  }
  if (i < N_NODES) rowptr[i] = sm[t] - v;   // exclusive
  if (t == 255) bsum[b] = sm[255];
}

__global__ void k_scan2(int* bsum, int* boff) {
  __shared__ int sm[256];
  int t = threadIdx.x;
  int v = (t < 196) ? bsum[t] : 0;
  sm[t] = v;
  __syncthreads();
#pragma unroll
  for (int off = 1; off < 256; off <<= 1) {
    int x = (t >= off) ? sm[t - off] : 0;
    __syncthreads();
    sm[t] += x;
    __syncthreads();
  }
  boff[t] = sm[t] - v;  // exclusive
}

__global__ void k_scan3(int* rowptr, const int* __restrict__ boff, int* counts) {
  int b = blockIdx.x, t = threadIdx.x;
  int i = b * 256 + t;
  if (i < N_NODES) {
    rowptr[i] += boff[b];
    counts[i] = 0;       // reuse as fill cursor
  }
  if (i == 0) rowptr[N_NODES] = N_EDGES;
}

__global__ void k_fill(const unsigned* __restrict__ e, const int* __restrict__ eflag,
                       const int* __restrict__ rowptr, int* counts, int* csr) {
  int i = blockIdx.x * 256 + threadIdx.x;
  if (i >= N_EDGES) return;
  int is64 = *eflag;
  int s = eidx(e, i, is64);
  int d = eidx(e, N_EDGES + i, is64);
  int pos = atomicAdd(&counts[d], 1);
  csr[rowptr[d] + pos] = s;
}

// ---- pack all 3 W (f32 [768][768] row-major -> bf16 fragment-major tiles) ----
__global__ void k_pack_w3(const float* __restrict__ W1, const float* __restrict__ W2,
                          const float* __restrict__ W3, ushort_t* __restrict__ pwbase) {
  int which = blockIdx.x / 288;
  int u = (blockIdx.x % 288) * 256 + threadIdx.x;   // 73728 units per W
  if (u >= 6 * 24 * 8 * 64) return;
  const float* W = which == 0 ? W1 : (which == 1 ? W2 : W3);
  ushort_t* pw = pwbase + (size_t)which * D_MODEL * D_MODEL;
  int c    = u & 15;
  int g    = (u >> 4) & 3;
  int cb16 = (u >> 6) & 7;
  int kt   = (u >> 9) % NKT;
  int cb   = u / (512 * NKT);
  int col  = cb * 128 + cb16 * 16 + c;
  ushort_t o[8];
#pragma unroll
  for (int j = 0; j < 8; ++j) {
    int k = kt * 32 + g * 4 + (j & 3) + 16 * (j >> 2);
    o[j] = f2bf(W[(size_t)k * D_MODEL + col]);
  }
  uint2 w0, w1;
  w0.x = (unsigned)o[0] | ((unsigned)o[1] << 16);
  w0.y = (unsigned)o[2] | ((unsigned)o[3] << 16);
  w1.x = (unsigned)o[4] | ((unsigned)o[5] << 16);
  w1.y = (unsigned)o[6] | ((unsigned)o[7] << 16);
  uint2* dst = (uint2*)(pw + (size_t)u * 8);
  dst[0] = w0; dst[1] = w1;
}

// ---- pack A for layer 1 (x f32 [N][768] -> bf16 fragment-major tiles) ----
__global__ void k_pack_a_f32(const float* __restrict__ X, ushort_t* __restrict__ pa) {
  __shared__ __align__(16) ushort_t sm[BM * BK];  // 8KB
  int bm = blockIdx.x, kt = blockIdx.y;
  int t = threadIdx.x;
#pragma unroll
  for (int i = 0; i < 4; ++i) {
    int idx = i * 256 + t;        // 0..1023 float4 units
    int row_l = idx >> 3;
    int q = idx & 7;              // which float4 in the 32-k row
    int row = bm * BM + row_l;
    float4 v = make_float4(0.f, 0.f, 0.f, 0.f);
    if (row < N_NODES)
      v = *(const float4*)(X + (size_t)row * D_MODEL + kt * 32 + q * 4);
    uint2 p;
    p.x = (unsigned)f2bf(v.x) | ((unsigned)f2bf(v.y) << 16);
    p.y = (unsigned)f2bf(v.z) | ((unsigned)f2bf(v.w) << 16);
    int off = (row_l >> 4) * 512 + (q & 3) * 128 + (row_l & 15) * 8 + (q >> 2) * 4;
    *(uint2*)(sm + off) = p;
  }
  __syncthreads();
  const uint4* s4 = (const uint4*)sm;           // 512 units
  uint4* d4 = (uint4*)pa + ((size_t)bm * NKT + kt) * 512;
  d4[t] = s4[t];
  d4[t + 256] = s4[t + 256];
}

// ---- GEMM: tmp'[row] = bf16( (A@W)[row] * dinv[row] ) ----
__global__ __launch_bounds__(256) void k_gemm(
    const ushort_t* __restrict__ pa, const ushort_t* __restrict__ pw,
    const float* __restrict__ dinv, ushort_t* __restrict__ tmp) {
  __shared__ __align__(16) char smem[2 * TILE_BYTES];  // A @0, B @8192
  const int qq = NWG / 8, rm = NWG % 8;
  int orig = blockIdx.x;
  int xcd = orig & 7, idx = orig >> 3;
  int wgid = (xcd < rm ? xcd * (qq + 1) : rm * (qq + 1) + (xcd - rm) * qq) + idx;
  int bm = wgid / NCB, cb = wgid % NCB;

  int t = threadIdx.x, w = t >> 6, l = t & 63;
  int wm = w >> 1, wn = w & 1;
  int g = l >> 4, r16 = l & 15;

  f32x4 acc[4][4] = {};

  const char* paT = (const char*)pa + (size_t)bm * NKT * TILE_BYTES;
  const char* pwT = (const char*)pw + (size_t)cb * NKT * TILE_BYTES;

  for (int kt = 0; kt < NKT; ++kt) {
    const char* ga = paT + (size_t)kt * TILE_BYTES;
    const char* gb = pwT + (size_t)kt * TILE_BYTES;
    int u = w * 2;
    gload_lds16(ga + (size_t)u * 1024 + (size_t)l * 16,       &smem[u * 1024]);
    gload_lds16(ga + (size_t)(u + 1) * 1024 + (size_t)l * 16, &smem[(u + 1) * 1024]);
    gload_lds16(gb + (size_t)u * 1024 + (size_t)l * 16,       &smem[TILE_BYTES + u * 1024]);
    gload_lds16(gb + (size_t)(u + 1) * 1024 + (size_t)l * 16, &smem[TILE_BYTES + (u + 1) * 1024]);
    __builtin_amdgcn_s_waitcnt(0);
    __syncthreads();

    bf16x8 af[4], bfr[4];
#pragma unroll
    for (int m = 0; m < 4; ++m)
      af[m] = *(const bf16x8*)&smem[(wm * 4 + m) * 1024 + g * 256 + r16 * 16];
#pragma unroll
    for (int n = 0; n < 4; ++n)
      bfr[n] = *(const bf16x8*)&smem[TILE_BYTES + (wn * 4 + n) * 1024 + g * 256 + r16 * 16];
#pragma unroll
    for (int m = 0; m < 4; ++m)
#pragma unroll
      for (int n = 0; n < 4; ++n)
        acc[m][n] = __builtin_amdgcn_mfma_f32_16x16x32_bf16(af[m], bfr[n], acc[m][n], 0, 0, 0);
    __syncthreads();
  }

  int colb = cb * 128 + wn * 64;
#pragma unroll
  for (int m = 0; m < 4; ++m) {
#pragma unroll
    for (int reg = 0; reg < 4; ++reg) {
      int row = bm * BM + wm * 64 + m * 16 + g * 4 + reg;
      if (row >= N_NODES) continue;
      float di = dinv[row];
      size_t base = (size_t)row * D_MODEL + colb;
#pragma unroll
      for (int n = 0; n < 4; ++n)
        tmp[base + n * 16 + r16] = f2bf(acc[m][n][reg] * di);
    }
  }
}

// ---- gather, layers 1&2: pa[r] = relu(dinv[r]*(tmp'[r]+sum tmp'[s]) + bias)
//   staged in LDS (packed-tile image, bank-swizzled), then written as 24
//   contiguous 1KB chunks (full-line writes). Two rows per wave in flight. ----
__global__ __launch_bounds__(256) void k_gather0(
    const int* __restrict__ rowptr, const int* __restrict__ csr,
    const float* __restrict__ dinv, const float* __restrict__ bias,
    const ushort_t* __restrict__ tmp, ushort_t* __restrict__ pa) {
  __shared__ __align__(16) char sraw[GROWS0 * D_MODEL * 2];  // 24KB
  __shared__ int srp[GROWS0 + 1];
  int t = threadIdx.x;
  int r0 = blockIdx.x * GROWS0;
  if (t <= GROWS0) srp[t] = rowptr[r0 + t];
  __syncthreads();

  int w = t >> 6, l = t & 63;
  const f32x4* b4 = (const f32x4*)bias;
  f32x4 bb0 = b4[l], bb1 = b4[l + 64], bb2 = b4[l + 128];
  int kt0 = l >> 3, q = l & 7;
  int qoffB = (q & 3) * 256 + (q >> 2) * 8;
  int swz = (kt0 & 7) << 4;

  for (int p = w; p < GROWS0 / 2; p += 4) {     // 2 rows per wave concurrently
    int iA = p, iB = p + GROWS0 / 2;
    int rA = r0 + iA, rB = r0 + iB;
    const uint2* rpA = (const uint2*)(tmp + (size_t)rA * D_MODEL);
    const uint2* rpB = (const uint2*)(tmp + (size_t)rB * D_MODEL);
    f32x4 a0 = unp4(rpA[l]), a1 = unp4(rpA[l + 64]), a2 = unp4(rpA[l + 128]);
    f32x4 c0 = unp4(rpB[l]), c1 = unp4(rpB[l + 64]), c2 = unp4(rpB[l + 128]);
    int jA = srp[iA], eA = srp[iA + 1];
    int jB = srp[iB], eB = srp[iB + 1];
    while (jA < eA && jB < eB) {
      int sA = csr[jA++], sB = csr[jB++];
      const uint2* pA = (const uint2*)(tmp + (size_t)sA * D_MODEL);
      const uint2* pB = (const uint2*)(tmp + (size_t)sB * D_MODEL);
      uint2 x0 = pA[l], x1 = pA[l + 64], x2 = pA[l + 128];
      uint2 y0 = pB[l], y1 = pB[l + 64], y2 = pB[l + 128];
      a0 += unp4(x0); a1 += unp4(x1); a2 += unp4(x2);
      c0 += unp4(y0); c1 += unp4(y1); c2 += unp4(y2);
    }
    while (jA < eA) {
      int sA = csr[jA++];
      const uint2* pA = (const uint2*)(tmp + (size_t)sA * D_MODEL);
      a0 += unp4(pA[l]); a1 += unp4(pA[l + 64]); a2 += unp4(pA[l + 128]);
    }
    while (jB < eB) {
      int sB = csr[jB++];
      const uint2* pB = (const uint2*)(tmp + (size_t)sB * D_MODEL);
      c0 += unp4(pB[l]); c1 += unp4(pB[l + 64]); c2 += unp4(pB[l + 128]);
    }
    float dA = dinv[rA], dB = dinv[rB];
    a0 = relu4(a0 * dA + bb0); a1 = relu4(a1 * dA + bb1); a2 = relu4(a2 * dA + bb2);
    c0 = relu4(c0 * dB + bb0); c1 = relu4(c1 * dB + bb1); c2 = relu4(c2 * dB + bb2);
    int baseA = (iA << 4) + qoffB, baseB = (iB << 4) + qoffB;
    char* sA0 = sraw + (((kt0 * 1024) + baseA) ^ swz);
    char* sB0 = sraw + (((kt0 * 1024) + baseB) ^ swz);
    *(uint2*)(sA0)         = pack4(a0);
    *(uint2*)(sA0 + 8192)  = pack4(a1);
    *(uint2*)(sA0 + 16384) = pack4(a2);
    *(uint2*)(sB0)         = pack4(c0);
    *(uint2*)(sB0 + 8192)  = pack4(c1);
    *(uint2*)(sB0 + 16384) = pack4(c2);
  }

  __syncthreads();
  // copy LDS image -> pa: 24 chunks of 1KB, contiguous
  int bm = r0 >> 7, rb0 = (r0 >> 4) & 7;
  size_t tilebase = ((size_t)bm * NKT) * TILE_ELEMS + (size_t)rb0 * 512;
#pragma unroll
  for (int it = 0; it < 6; ++it) {
    int byte = (it * 256 + t) * 16;            // 0..24575
    int kt = byte >> 10;
    uint4 v = *(const uint4*)(sraw + (byte ^ ((kt & 7) << 4)));
    *(uint4*)((char*)(pa + tilebase + (size_t)kt * TILE_ELEMS) + (byte & 1023)) = v;
  }
}

// ---- gather, layer 3: hout[r] = relu(dinv*(...)+bias) + x[r] (f32) + colsum.
//   Single row per wave iteration, 2-way edge unroll, x prefetched early. ----
__global__ __launch_bounds__(256) void k_gather1(
    const int* __restrict__ rowptr, const int* __restrict__ csr,
    const float* __restrict__ dinv, const float* __restrict__ bias,
    const ushort_t* __restrict__ tmp, const float* __restrict__ x,
    float* __restrict__ hout, float* __restrict__ colsum) {
  __shared__ float cs[768];
  __shared__ int srp[GROWS1 + 1];
  int t = threadIdx.x;
  int r0 = blockIdx.x * GROWS1;
  if (t <= GROWS1) srp[t] = rowptr[r0 + t];
  cs[t] = 0.f; cs[t + 256] = 0.f; cs[t + 512] = 0.f;
  __syncthreads();

  int w = t >> 6, l = t & 63;
  const f32x4* b4 = (const f32x4*)bias;
  f32x4 bb0 = b4[l], bb1 = b4[l + 64], bb2 = b4[l + 128];
  f32x4 s0 = {0.f, 0.f, 0.f, 0.f}, s1 = s0, s2 = s0;

  for (int rr = w; rr < GROWS1; rr += 4) {
    int r = r0 + rr;
    // issue x-residual loads early: they overlap the dependent edge chain
    const f32x4* xp = (const f32x4*)(x + (size_t)r * D_MODEL);
    f32x4 x0 = xp[l], x1 = xp[l + 64], x2 = xp[l + 128];
    const uint2* rp = (const uint2*)(tmp + (size_t)r * D_MODEL);
    f32x4 a0 = unp4(rp[l]), a1 = unp4(rp[l + 64]), a2 = unp4(rp[l + 128]);
    int j = srp[rr], end = srp[rr + 1];
    for (; j + 2 <= end; j += 2) {
      int sa = csr[j], sb = csr[j + 1];
      const uint2* pA = (const uint2*)(tmp + (size_t)sa * D_MODEL);
      const uint2* pB = (const uint2*)(tmp + (size_t)sb * D_MODEL);
      uint2 va0 = pA[l], va1 = pA[l + 64], va2 = pA[l + 128];
      uint2 vb0 = pB[l], vb1 = pB[l + 64], vb2 = pB[l + 128];
      a0 += unp4(va0) + unp4(vb0);
      a1 += unp4(va1) + unp4(vb1);
      a2 += unp4(va2) + unp4(vb2);
    }
    if (j < end) {
      int s = csr[j];
      const uint2* sp = (const uint2*)(tmp + (size_t)s * D_MODEL);
      a0 += unp4(sp[l]); a1 += unp4(sp[l + 64]); a2 += unp4(sp[l + 128]);
    }
    float di = dinv[r];
    a0 = relu4(a0 * di + bb0) + x0;
    a1 = relu4(a1 * di + bb1) + x1;
    a2 = relu4(a2 * di + bb2) + x2;
    f32x4* op = (f32x4*)(hout + (size_t)r * D_MODEL);
    op[l] = a0; op[l + 64] = a1; op[l + 128] = a2;
    s0 += a0; s1 += a1; s2 += a2;
  }

#pragma unroll
  for (int c = 0; c < 4; ++c) {
    atomicAdd(&cs[4 * l + c],       s0[c]);
    atomicAdd(&cs[256 + 4 * l + c], s1[c]);
    atomicAdd(&cs[512 + 4 * l + c], s2[c]);
  }
  __syncthreads();
  atomicAdd(&colsum[t],       cs[t]);
  atomicAdd(&colsum[t + 256], cs[t + 256]);
  atomicAdd(&colsum[t + 512], cs[t + 512]);
}

// ---- final: out = (colsum/N) @ Wl + bl ----
__global__ void k_final(const float* __restrict__ colsum, const float* __restrict__ Wl,
                        const float* __restrict__ bl, float* __restrict__ out) {
  int j = blockIdx.x * 128 + threadIdx.x;
  if (j >= D_MODEL) return;
  float s = 0.f;
  for (int k = 0; k < D_MODEL; ++k)
    s += colsum[k] * Wl[(size_t)k * D_MODEL + j];
  out[j] = s * (1.0f / (float)N_NODES) + bl[j];
}

extern "C" void kernel_launch(void* const* d_in, const int* in_sizes, int n_in,
                              void* d_out, int out_size, void* d_ws, size_t ws_size,
                              hipStream_t stream) {
  const float* x      = (const float*)d_in[0];
  const unsigned* edg = (const unsigned*)d_in[1];
  const float* W1 = (const float*)d_in[2];
  const float* b1 = (const float*)d_in[3];
  const float* W2 = (const float*)d_in[4];
  const float* b2 = (const float*)d_in[5];
  const float* W3 = (const float*)d_in[6];
  const float* b3 = (const float*)d_in[7];
  const float* Wl = (const float*)d_in[8];
  const float* bl = (const float*)d_in[9];

  float* hout = (float*)d_out;
  float* oout = hout + (size_t)N_NODES * D_MODEL;

  char* ws = (char*)d_ws;
  size_t off = 0;
  ushort_t* tmp = (ushort_t*)(ws + off); off += (size_t)N_NODES * D_MODEL * 2;  // 76.8 MB
  ushort_t* pa = (ushort_t*)(ws + off);  off += (size_t)M_PAD * D_MODEL * 2;    // 76.9 MB
  ushort_t* pw0 = (ushort_t*)(ws + off); off += (size_t)D_MODEL * D_MODEL * 2;
  ushort_t* pw1 = (ushort_t*)(ws + off); off += (size_t)D_MODEL * D_MODEL * 2;
  ushort_t* pw2 = (ushort_t*)(ws + off); off += (size_t)D_MODEL * D_MODEL * 2;
  float* dinv = (float*)(ws + off);      off += 50176 * 4;
  int* counts = (int*)(ws + off);        off += 50176 * 4;
  int* rowptr = (int*)(ws + off);        off += 50304 * 4;
  int* csr = (int*)(ws + off);           off += (size_t)N_EDGES * 4;
  int* bsum = (int*)(ws + off);          off += 256 * 4;
  int* boff = (int*)(ws + off);          off += 256 * 4;
  float* colsum = (float*)(ws + off);    off += 1024;
  int* eflag = (int*)(ws + off);         off += 256;

  // setup (edge structure is static across layers)
  k_init<<<196, 256, 0, stream>>>(edg, counts, colsum, eflag);
  k_count<<<391, 256, 0, stream>>>(edg, eflag, counts);
  k_scan1<<<196, 256, 0, stream>>>(counts, rowptr, bsum, dinv);
  k_scan2<<<1, 256, 0, stream>>>(bsum, boff);
  k_scan3<<<196, 256, 0, stream>>>(rowptr, boff, counts);
  k_fill<<<391, 256, 0, stream>>>(edg, eflag, rowptr, counts, csr);
  k_pack_w3<<<864, 256, 0, stream>>>(W1, W2, W3, pw0);

  k_pack_a_f32<<<dim3(MBLOCKS, NKT), 256, 0, stream>>>(x, pa);

  // layer 1
  k_gemm<<<NWG, 256, 0, stream>>>(pa, pw0, dinv, tmp);
  k_gather0<<<N_NODES / GROWS0, 256, 0, stream>>>(rowptr, csr, dinv, b1, tmp, pa);
  // layer 2
  k_gemm<<<NWG, 256, 0, stream>>>(pa, pw1, dinv, tmp);
  k_gather0<<<N_NODES / GROWS0, 256, 0, stream>>>(rowptr, csr, dinv, b2, tmp, pa);
  // layer 3 (fused relu + residual + colsum)
  k_gemm<<<NWG, 256, 0, stream>>>(pa, pw2, dinv, tmp);
  k_gather1<<<(N_NODES + GROWS1 - 1) / GROWS1, 256, 0, stream>>>(
      rowptr, csr, dinv, b3, tmp, x, hout, colsum);

  k_final<<<6, 128, 0, stream>>>(colsum, Wl, bl, oout);
}

// Round 7
// 563.716 us; speedup vs baseline: 2.6907x; 1.0701x over previous
//
#include <hip/hip_runtime.h>
#include <stdint.h>

#define N_NODES 50000
#define D_MODEL 768
#define N_EDGES 100000
#define BM 128
#define NKT 24                 /* 768/32 */
#define MBLOCKS 391            /* ceil(50000/128) */
#define M_PAD (MBLOCKS * BM)   /* 50048 */
#define NCB 6                  /* 768/128 */
#define TILE_BYTES 8192        /* 128*32*2 */
#define TILE_ELEMS 4096
#define NWG (MBLOCKS * NCB)    /* 2346 */
#define GROWS0 16              /* gather rows/block (LDS-staged) */

typedef unsigned short ushort_t;
typedef __bf16 bf16x8 __attribute__((ext_vector_type(8)));
typedef float f32x4 __attribute__((ext_vector_type(4)));

__device__ __forceinline__ unsigned short f2bf(float f) {
  union { float f; unsigned u; } v; v.f = f;
  unsigned r = v.u + 0x7fffu + ((v.u >> 16) & 1u);
  return (unsigned short)(r >> 16);
}

__device__ __forceinline__ uint2 pack4(f32x4 v) {
  uint2 p;
  p.x = (unsigned)f2bf(v[0]) | ((unsigned)f2bf(v[1]) << 16);
  p.y = (unsigned)f2bf(v[2]) | ((unsigned)f2bf(v[3]) << 16);
  return p;
}

__device__ __forceinline__ f32x4 unp4(uint2 p) {
  union { unsigned u; float f; } c;
  f32x4 v;
  c.u = p.x << 16;          v[0] = c.f;
  c.u = p.x & 0xffff0000u;  v[1] = c.f;
  c.u = p.y << 16;          v[2] = c.f;
  c.u = p.y & 0xffff0000u;  v[3] = c.f;
  return v;
}

__device__ __forceinline__ void gload_lds16(const void* g, void* l) {
  __builtin_amdgcn_global_load_lds(
      (const __attribute__((address_space(1))) unsigned int*)g,
      (__attribute__((address_space(3))) unsigned int*)l, 16, 0, 0);
}

__device__ __forceinline__ int eidx(const unsigned* e, int logical, int is64) {
  return is64 ? (int)e[2 * logical] : (int)e[logical];
}

// ---- init: zero counts + colsum; block 0 also does edge-dtype detect ----
__global__ void k_init(const unsigned* __restrict__ e, int* counts, float* colsum,
                       int* eflag) {
  int i = blockIdx.x * 256 + threadIdx.x;
  if (i < N_NODES) counts[i] = 0;
  if (i < D_MODEL) colsum[i] = 0.0f;
  if (i == 0) {
    int is64 = 1;
    for (int k = 0; k < 64; ++k)
      if (e[2 * k + 1] != 0u) { is64 = 0; break; }
    *eflag = is64;
  }
}

__global__ void k_count(const unsigned* __restrict__ e, const int* __restrict__ eflag,
                        int* counts) {
  int i = blockIdx.x * 256 + threadIdx.x;
  if (i >= N_EDGES) return;
  int is64 = *eflag;
  int d = eidx(e, N_EDGES + i, is64);
  atomicAdd(&counts[d], 1);
}

// ---- CSR build: 3-phase exclusive scan of counts -> rowptr, then fill ----
__global__ void k_scan1(const int* __restrict__ counts, int* rowptr, int* bsum,
                        float* dinv) {
  __shared__ int sm[256];
  int b = blockIdx.x, t = threadIdx.x;
  int i = b * 256 + t;
  int v = (i < N_NODES) ? counts[i] : 0;
  if (i < N_NODES) dinv[i] = rsqrtf((float)(v + 1));  // deg = 1 + indeg
  sm[t] = v;
  __syncthreads();
#pragma unroll
  for (int off = 1; off < 256; off <<= 1) {
    int x = (t >= off) ? sm[t - off] : 0;
    __syncthreads();
    sm[t] += x;
    __syncthreads();
  }
  if (i < N_NODES) rowptr[i] = sm[t] - v;   // exclusive
  if (t == 255) bsum[b] = sm[255];
}

__global__ void k_scan2(int* bsum, int* boff) {
  __shared__ int sm[256];
  int t = threadIdx.x;
  int v = (t < 196) ? bsum[t] : 0;
  sm[t] = v;
  __syncthreads();
#pragma unroll
  for (int off = 1; off < 256; off <<= 1) {
    int x = (t >= off) ? sm[t - off] : 0;
    __syncthreads();
    sm[t] += x;
    __syncthreads();
  }
  boff[t] = sm[t] - v;  // exclusive
}

__global__ void k_scan3(int* rowptr, const int* __restrict__ boff, int* counts) {
  int b = blockIdx.x, t = threadIdx.x;
  int i = b * 256 + t;
  if (i < N_NODES) {
    rowptr[i] += boff[b];
    counts[i] = 0;       // reuse as fill cursor
  }
  if (i == 0) rowptr[N_NODES] = N_EDGES;
}

__global__ void k_fill(const unsigned* __restrict__ e, const int* __restrict__ eflag,
                       const int* __restrict__ rowptr, int* counts, int* csr) {
  int i = blockIdx.x * 256 + threadIdx.x;
  if (i >= N_EDGES) return;
  int is64 = *eflag;
  int s = eidx(e, i, is64);
  int d = eidx(e, N_EDGES + i, is64);
  int pos = atomicAdd(&counts[d], 1);
  csr[rowptr[d] + pos] = s;
}

// ---- pack all 3 W (f32 [768][768] row-major -> bf16 fragment-major tiles) ----
__global__ void k_pack_w3(const float* __restrict__ W1, const float* __restrict__ W2,
                          const float* __restrict__ W3, ushort_t* __restrict__ pwbase) {
  int which = blockIdx.x / 288;
  int u = (blockIdx.x % 288) * 256 + threadIdx.x;   // 73728 units per W
  if (u >= 6 * 24 * 8 * 64) return;
  const float* W = which == 0 ? W1 : (which == 1 ? W2 : W3);
  ushort_t* pw = pwbase + (size_t)which * D_MODEL * D_MODEL;
  int c    = u & 15;
  int g    = (u >> 4) & 3;
  int cb16 = (u >> 6) & 7;
  int kt   = (u >> 9) % NKT;
  int cb   = u / (512 * NKT);
  int col  = cb * 128 + cb16 * 16 + c;
  ushort_t o[8];
#pragma unroll
  for (int j = 0; j < 8; ++j) {
    int k = kt * 32 + g * 4 + (j & 3) + 16 * (j >> 2);
    o[j] = f2bf(W[(size_t)k * D_MODEL + col]);
  }
  uint2 w0, w1;
  w0.x = (unsigned)o[0] | ((unsigned)o[1] << 16);
  w0.y = (unsigned)o[2] | ((unsigned)o[3] << 16);
  w1.x = (unsigned)o[4] | ((unsigned)o[5] << 16);
  w1.y = (unsigned)o[6] | ((unsigned)o[7] << 16);
  uint2* dst = (uint2*)(pw + (size_t)u * 8);
  dst[0] = w0; dst[1] = w1;
}

// ---- t0 = bf16(dinv * x), row-major ----
__global__ void k_scale_x(const float* __restrict__ x, const float* __restrict__ dinv,
                          ushort_t* __restrict__ t) {
  int idx = (blockIdx.x * 256 + threadIdx.x) * 8;
  if (idx >= N_NODES * D_MODEL) return;
  float di = dinv[idx / D_MODEL];      // 768 % 8 == 0 -> chunk within one row
  float4 v0 = *(const float4*)(x + idx);
  float4 v1 = *(const float4*)(x + idx + 4);
  uint4 o;
  o.x = (unsigned)f2bf(v0.x * di) | ((unsigned)f2bf(v0.y * di) << 16);
  o.y = (unsigned)f2bf(v0.z * di) | ((unsigned)f2bf(v0.w * di) << 16);
  o.z = (unsigned)f2bf(v1.x * di) | ((unsigned)f2bf(v1.y * di) << 16);
  o.w = (unsigned)f2bf(v1.z * di) | ((unsigned)f2bf(v1.w * di) << 16);
  *(uint4*)(t + idx) = o;
}

// ---- gather_agg (all layers): pagg[r] = dinv[r]*(t[r] + sum_in t[s]),
//   packed bf16 via LDS-staged image, full-line 1KB writes. ----
__global__ __launch_bounds__(256) void k_gather_agg(
    const int* __restrict__ rowptr, const int* __restrict__ csr,
    const float* __restrict__ dinv, const ushort_t* __restrict__ t,
    ushort_t* __restrict__ pagg) {
  __shared__ __align__(16) char sraw[GROWS0 * D_MODEL * 2];  // 24KB
  __shared__ int srp[GROWS0 + 1];
  int tid = threadIdx.x;
  int r0 = blockIdx.x * GROWS0;
  if (tid <= GROWS0) srp[tid] = rowptr[r0 + tid];
  __syncthreads();

  int w = tid >> 6, l = tid & 63;
  int kt0 = l >> 3, q = l & 7;
  int qoffB = (q & 3) * 256 + (q >> 2) * 8;
  int swz = kt0 << 4;

  for (int p = w; p < GROWS0 / 2; p += 4) {     // 2 rows per wave concurrently
    int iA = p, iB = p + GROWS0 / 2;
    int rA = r0 + iA, rB = r0 + iB;
    const uint2* rpA = (const uint2*)(t + (size_t)rA * D_MODEL);
    const uint2* rpB = (const uint2*)(t + (size_t)rB * D_MODEL);
    f32x4 a0 = unp4(rpA[l]), a1 = unp4(rpA[l + 64]), a2 = unp4(rpA[l + 128]);
    f32x4 c0 = unp4(rpB[l]), c1 = unp4(rpB[l + 64]), c2 = unp4(rpB[l + 128]);
    int jA = srp[iA], eA = srp[iA + 1];
    int jB = srp[iB], eB = srp[iB + 1];
    while (jA < eA && jB < eB) {
      int sA = csr[jA++], sB = csr[jB++];
      const uint2* pA = (const uint2*)(t + (size_t)sA * D_MODEL);
      const uint2* pB = (const uint2*)(t + (size_t)sB * D_MODEL);
      uint2 x0 = pA[l], x1 = pA[l + 64], x2 = pA[l + 128];
      uint2 y0 = pB[l], y1 = pB[l + 64], y2 = pB[l + 128];
      a0 += unp4(x0); a1 += unp4(x1); a2 += unp4(x2);
      c0 += unp4(y0); c1 += unp4(y1); c2 += unp4(y2);
    }
    while (jA < eA) {
      int sA = csr[jA++];
      const uint2* pA = (const uint2*)(t + (size_t)sA * D_MODEL);
      a0 += unp4(pA[l]); a1 += unp4(pA[l + 64]); a2 += unp4(pA[l + 128]);
    }
    while (jB < eB) {
      int sB = csr[jB++];
      const uint2* pB = (const uint2*)(t + (size_t)sB * D_MODEL);
      c0 += unp4(pB[l]); c1 += unp4(pB[l + 64]); c2 += unp4(pB[l + 128]);
    }
    float dA = dinv[rA], dB = dinv[rB];
    a0 *= dA; a1 *= dA; a2 *= dA;
    c0 *= dB; c1 *= dB; c2 *= dB;
    int baseA = (iA << 4) + qoffB, baseB = (iB << 4) + qoffB;
    char* sA0 = sraw + (((kt0 * 1024) + baseA) ^ swz);
    char* sB0 = sraw + (((kt0 * 1024) + baseB) ^ swz);
    *(uint2*)(sA0)         = pack4(a0);
    *(uint2*)(sA0 + 8192)  = pack4(a1);
    *(uint2*)(sA0 + 16384) = pack4(a2);
    *(uint2*)(sB0)         = pack4(c0);
    *(uint2*)(sB0 + 8192)  = pack4(c1);
    *(uint2*)(sB0 + 16384) = pack4(c2);
  }

  __syncthreads();
  // copy LDS image -> pagg: 24 chunks of 1KB, contiguous
  int bm = r0 >> 7, rb0 = (r0 >> 4) & 7;
  size_t tilebase = ((size_t)bm * NKT) * TILE_ELEMS + (size_t)rb0 * 512;
#pragma unroll
  for (int it = 0; it < 6; ++it) {
    int byte = (it * 256 + tid) * 16;            // 0..24575
    int kt = byte >> 10;
    uint4 v = *(const uint4*)(sraw + (byte ^ ((kt & 7) << 4)));
    *(uint4*)((char*)(pagg + tilebase + (size_t)kt * TILE_ELEMS) + (byte & 1023)) = v;
  }
}

// ---- GEMM core macro pieces (BK=64: two 8KB kt-tiles per stage) ----
// layers 1,2: t[row] = bf16( dinv[row] * relu( (agg@W)[row] + b ) ), row-major
__global__ __launch_bounds__(256) void k_gemm12(
    const ushort_t* __restrict__ pa, const ushort_t* __restrict__ pw,
    const float* __restrict__ dinv, const float* __restrict__ bias,
    ushort_t* __restrict__ tout) {
  __shared__ __align__(16) char smem[4 * TILE_BYTES];  // A0,A1 @0; B0,B1 @16384
  const int qq = NWG / 8, rm = NWG % 8;
  int orig = blockIdx.x;
  int xcd = orig & 7, idx = orig >> 3;
  int wgid = (xcd < rm ? xcd * (qq + 1) : rm * (qq + 1) + (xcd - rm) * qq) + idx;
  int bm = wgid / NCB, cb = wgid % NCB;

  int t = threadIdx.x, w = t >> 6, l = t & 63;
  int wm = w >> 1, wn = w & 1;
  int g = l >> 4, r16 = l & 15;

  f32x4 acc[4][4] = {};

  const char* paT = (const char*)pa + (size_t)bm * NKT * TILE_BYTES;
  const char* pwT = (const char*)pw + (size_t)cb * NKT * TILE_BYTES;

  for (int kt = 0; kt < NKT; kt += 2) {
    const char* ga = paT + (size_t)kt * TILE_BYTES;
    const char* gb = pwT + (size_t)kt * TILE_BYTES;
    int u = w * 2;
    gload_lds16(ga + (size_t)u * 1024 + (size_t)l * 16,              &smem[u * 1024]);
    gload_lds16(ga + (size_t)(u + 1) * 1024 + (size_t)l * 16,        &smem[(u + 1) * 1024]);
    gload_lds16(ga + 8192 + (size_t)u * 1024 + (size_t)l * 16,       &smem[8192 + u * 1024]);
    gload_lds16(ga + 8192 + (size_t)(u + 1) * 1024 + (size_t)l * 16, &smem[8192 + (u + 1) * 1024]);
    gload_lds16(gb + (size_t)u * 1024 + (size_t)l * 16,              &smem[16384 + u * 1024]);
    gload_lds16(gb + (size_t)(u + 1) * 1024 + (size_t)l * 16,        &smem[16384 + (u + 1) * 1024]);
    gload_lds16(gb + 8192 + (size_t)u * 1024 + (size_t)l * 16,       &smem[24576 + u * 1024]);
    gload_lds16(gb + 8192 + (size_t)(u + 1) * 1024 + (size_t)l * 16, &smem[24576 + (u + 1) * 1024]);
    __builtin_amdgcn_s_waitcnt(0);
    __syncthreads();

#pragma unroll
    for (int h = 0; h < 2; ++h) {
      bf16x8 af[4], bfr[4];
#pragma unroll
      for (int m = 0; m < 4; ++m)
        af[m] = *(const bf16x8*)&smem[h * 8192 + (wm * 4 + m) * 1024 + g * 256 + r16 * 16];
#pragma unroll
      for (int n = 0; n < 4; ++n)
        bfr[n] = *(const bf16x8*)&smem[16384 + h * 8192 + (wn * 4 + n) * 1024 + g * 256 + r16 * 16];
#pragma unroll
      for (int m = 0; m < 4; ++m)
#pragma unroll
        for (int n = 0; n < 4; ++n)
          acc[m][n] = __builtin_amdgcn_mfma_f32_16x16x32_bf16(af[m], bfr[n], acc[m][n], 0, 0, 0);
    }
    __syncthreads();
  }

  int colb = cb * 128 + wn * 64;
  float bn[4];
#pragma unroll
  for (int n = 0; n < 4; ++n) bn[n] = bias[colb + n * 16 + r16];
#pragma unroll
  for (int m = 0; m < 4; ++m) {
#pragma unroll
    for (int reg = 0; reg < 4; ++reg) {
      int row = bm * BM + wm * 64 + m * 16 + g * 4 + reg;
      if (row >= N_NODES) continue;
      float di = dinv[row];
      size_t base = (size_t)row * D_MODEL + colb;
#pragma unroll
      for (int n = 0; n < 4; ++n)
        tout[base + n * 16 + r16] = f2bf(di * fmaxf(acc[m][n][reg] + bn[n], 0.f));
    }
  }
}

// layer 3: hout[row] = relu((agg@W3)[row] + b3) + x[row] (f32) + colsum reduce
__global__ __launch_bounds__(256) void k_gemm3(
    const ushort_t* __restrict__ pa, const ushort_t* __restrict__ pw,
    const float* __restrict__ bias, const float* __restrict__ x,
    float* __restrict__ hout, float* __restrict__ colsum) {
  __shared__ __align__(16) char smem[4 * TILE_BYTES];
  __shared__ float scol[128];
  const int qq = NWG / 8, rm = NWG % 8;
  int orig = blockIdx.x;
  int xcd = orig & 7, idx = orig >> 3;
  int wgid = (xcd < rm ? xcd * (qq + 1) : rm * (qq + 1) + (xcd - rm) * qq) + idx;
  int bm = wgid / NCB, cb = wgid % NCB;

  int t = threadIdx.x, w = t >> 6, l = t & 63;
  int wm = w >> 1, wn = w & 1;
  int g = l >> 4, r16 = l & 15;

  f32x4 acc[4][4] = {};

  const char* paT = (const char*)pa + (size_t)bm * NKT * TILE_BYTES;
  const char* pwT = (const char*)pw + (size_t)cb * NKT * TILE_BYTES;

  for (int kt = 0; kt < NKT; kt += 2) {
    const char* ga = paT + (size_t)kt * TILE_BYTES;
    const char* gb = pwT + (size_t)kt * TILE_BYTES;
    int u = w * 2;
    gload_lds16(ga + (size_t)u * 1024 + (size_t)l * 16,              &smem[u * 1024]);
    gload_lds16(ga + (size_t)(u + 1) * 1024 + (size_t)l * 16,        &smem[(u + 1) * 1024]);
    gload_lds16(ga + 8192 + (size_t)u * 1024 + (size_t)l * 16,       &smem[8192 + u * 1024]);
    gload_lds16(ga + 8192 + (size_t)(u + 1) * 1024 + (size_t)l * 16, &smem[8192 + (u + 1) * 1024]);
    gload_lds16(gb + (size_t)u * 1024 + (size_t)l * 16,              &smem[16384 + u * 1024]);
    gload_lds16(gb + (size_t)(u + 1) * 1024 + (size_t)l * 16,        &smem[16384 + (u + 1) * 1024]);
    gload_lds16(gb + 8192 + (size_t)u * 1024 + (size_t)l * 16,       &smem[24576 + u * 1024]);
    gload_lds16(gb + 8192 + (size_t)(u + 1) * 1024 + (size_t)l * 16, &smem[24576 + (u + 1) * 1024]);
    __builtin_amdgcn_s_waitcnt(0);
    __syncthreads();

#pragma unroll
    for (int h = 0; h < 2; ++h) {
      bf16x8 af[4], bfr[4];
#pragma unroll
      for (int m = 0; m < 4; ++m)
        af[m] = *(const bf16x8*)&smem[h * 8192 + (wm * 4 + m) * 1024 + g * 256 + r16 * 16];
#pragma unroll
      for (int n = 0; n < 4; ++n)
        bfr[n] = *(const bf16x8*)&smem[16384 + h * 8192 + (wn * 4 + n) * 1024 + g * 256 + r16 * 16];
#pragma unroll
      for (int m = 0; m < 4; ++m)
#pragma unroll
        for (int n = 0; n < 4; ++n)
          acc[m][n] = __builtin_amdgcn_mfma_f32_16x16x32_bf16(af[m], bfr[n], acc[m][n], 0, 0, 0);
    }
    __syncthreads();
  }

  if (t < 128) scol[t] = 0.f;
  __syncthreads();

  int colb = cb * 128 + wn * 64;
  float bn[4];
#pragma unroll
  for (int n = 0; n < 4; ++n) bn[n] = bias[colb + n * 16 + r16];
  float cp[4] = {0.f, 0.f, 0.f, 0.f};
#pragma unroll
  for (int m = 0; m < 4; ++m) {
#pragma unroll
    for (int reg = 0; reg < 4; ++reg) {
      int row = bm * BM + wm * 64 + m * 16 + g * 4 + reg;
      if (row >= N_NODES) continue;
      size_t base = (size_t)row * D_MODEL + colb;
#pragma unroll
      for (int n = 0; n < 4; ++n) {
        float v = fmaxf(acc[m][n][reg] + bn[n], 0.f) + x[base + n * 16 + r16];
        hout[base + n * 16 + r16] = v;
        cp[n] += v;
      }
    }
  }
#pragma unroll
  for (int n = 0; n < 4; ++n)
    atomicAdd(&scol[wn * 64 + n * 16 + r16], cp[n]);
  __syncthreads();
  if (t < 128) atomicAdd(&colsum[cb * 128 + t], scol[t]);
}

// ---- final: out = (colsum/N) @ Wl + bl ----
__global__ void k_final(const float* __restrict__ colsum, const float* __restrict__ Wl,
                        const float* __restrict__ bl, float* __restrict__ out) {
  int j = blockIdx.x * 128 + threadIdx.x;
  if (j >= D_MODEL) return;
  float s = 0.f;
  for (int k = 0; k < D_MODEL; ++k)
    s += colsum[k] * Wl[(size_t)k * D_MODEL + j];
  out[j] = s * (1.0f / (float)N_NODES) + bl[j];
}

extern "C" void kernel_launch(void* const* d_in, const int* in_sizes, int n_in,
                              void* d_out, int out_size, void* d_ws, size_t ws_size,
                              hipStream_t stream) {
  const float* x      = (const float*)d_in[0];
  const unsigned* edg = (const unsigned*)d_in[1];
  const float* W1 = (const float*)d_in[2];
  const float* b1 = (const float*)d_in[3];
  const float* W2 = (const float*)d_in[4];
  const float* b2 = (const float*)d_in[5];
  const float* W3 = (const float*)d_in[6];
  const float* b3 = (const float*)d_in[7];
  const float* Wl = (const float*)d_in[8];
  const float* bl = (const float*)d_in[9];

  float* hout = (float*)d_out;
  float* oout = hout + (size_t)N_NODES * D_MODEL;

  char* ws = (char*)d_ws;
  size_t off = 0;
  ushort_t* t = (ushort_t*)(ws + off);   off += (size_t)N_NODES * D_MODEL * 2;  // 76.8 MB
  ushort_t* pagg = (ushort_t*)(ws + off); off += (size_t)M_PAD * D_MODEL * 2;   // 76.9 MB
  ushort_t* pw0 = (ushort_t*)(ws + off); off += (size_t)D_MODEL * D_MODEL * 2;
  ushort_t* pw1 = (ushort_t*)(ws + off); off += (size_t)D_MODEL * D_MODEL * 2;
  ushort_t* pw2 = (ushort_t*)(ws + off); off += (size_t)D_MODEL * D_MODEL * 2;
  float* dinv = (float*)(ws + off);      off += 50176 * 4;
  int* counts = (int*)(ws + off);        off += 50176 * 4;
  int* rowptr = (int*)(ws + off);        off += 50304 * 4;
  int* csr = (int*)(ws + off);           off += (size_t)N_EDGES * 4;
  int* bsum = (int*)(ws + off);          off += 256 * 4;
  int* boff = (int*)(ws + off);          off += 256 * 4;
  float* colsum = (float*)(ws + off);    off += 1024;
  int* eflag = (int*)(ws + off);         off += 256;

  // setup (edge structure is static across layers)
  k_init<<<196, 256, 0, stream>>>(edg, counts, colsum, eflag);
  k_count<<<391, 256, 0, stream>>>(edg, eflag, counts);
  k_scan1<<<196, 256, 0, stream>>>(counts, rowptr, bsum, dinv);
  k_scan2<<<1, 256, 0, stream>>>(bsum, boff);
  k_scan3<<<196, 256, 0, stream>>>(rowptr, boff, counts);
  k_fill<<<391, 256, 0, stream>>>(edg, eflag, rowptr, counts, csr);
  k_pack_w3<<<864, 256, 0, stream>>>(W1, W2, W3, pw0);
  k_scale_x<<<18750, 256, 0, stream>>>(x, dinv, t);

  const int NGB = N_NODES / GROWS0;  // 3125
  // layer 1
  k_gather_agg<<<NGB, 256, 0, stream>>>(rowptr, csr, dinv, t, pagg);
  k_gemm12<<<NWG, 256, 0, stream>>>(pagg, pw0, dinv, b1, t);
  // layer 2
  k_gather_agg<<<NGB, 256, 0, stream>>>(rowptr, csr, dinv, t, pagg);
  k_gemm12<<<NWG, 256, 0, stream>>>(pagg, pw1, dinv, b2, t);
  // layer 3 (epilogue fuses bias+relu+residual+colsum, f32 out)
  k_gather_agg<<<NGB, 256, 0, stream>>>(rowptr, csr, dinv, t, pagg);
  k_gemm3<<<NWG, 256, 0, stream>>>(pagg, pw2, b3, x, hout, colsum);

  k_final<<<6, 128, 0, stream>>>(colsum, Wl, bl, oout);
}